// Round 10
// baseline (146.641 us; speedup 1.0000x reference)
//
#include <hip/hip_runtime.h>

typedef __attribute__((ext_vector_type(8))) short bf16x8;
typedef __attribute__((ext_vector_type(4))) float f32x4;
typedef __attribute__((ext_vector_type(8))) unsigned short u16x8;

#define BB 32
#define NN 1024
#define MM 256
#define HH 128

__device__ __forceinline__ unsigned short f2bf(float f) {
  union { float f; unsigned int u; } c; c.f = f;
  unsigned int u = c.u + 0x7fffu + ((c.u >> 16) & 1u);  // RNE
  return (unsigned short)(u >> 16);
}
__device__ __forceinline__ unsigned int cvtpk(float lo, float hi) {
  unsigned int r;
  asm("v_cvt_pk_bf16_f32 %0, %1, %2" : "=v"(r) : "v"(lo), "v"(hi));
  return r;
}

// ---------- combined pre-pass: hT (bf16 [B][M][N]) + W1T/W2T ----------
__global__ __launch_bounds__(256)
void k_prep(const float* __restrict__ hg, unsigned short* __restrict__ hTg,
            const float* __restrict__ W1, const float* __restrict__ W2,
            unsigned short* __restrict__ W1T, unsigned short* __restrict__ W2T) {
  int bid = blockIdx.x;
  if (bid < BB * 64) {
    __shared__ unsigned short tile[64][65];
    int b = bid >> 6;
    int t = bid & 63;
    int k0 = (t >> 2) << 6;
    int m0 = (t & 3) << 6;
    int tt = threadIdx.x;
    {
      int r = tt >> 2;
      int cg = (tt & 3) << 4;
      const float* src = hg + (((size_t)b * NN + k0 + r) * MM + m0 + cg);
#pragma unroll
      for (int i = 0; i < 4; ++i) {
        float4 v = reinterpret_cast<const float4*>(src)[i];
        tile[r][cg + i * 4 + 0] = f2bf(v.x);
        tile[r][cg + i * 4 + 1] = f2bf(v.y);
        tile[r][cg + i * 4 + 2] = f2bf(v.z);
        tile[r][cg + i * 4 + 3] = f2bf(v.w);
      }
    }
    __syncthreads();
    {
      int mr = tt >> 2;
      int kc = (tt & 3) << 4;
      alignas(16) unsigned short tmp[16];
#pragma unroll
      for (int i = 0; i < 16; ++i) tmp[i] = tile[kc + i][mr];
      unsigned short* dst = hTg + (((size_t)b * MM + m0 + mr) * NN + k0 + kc);
      *reinterpret_cast<u16x8*>(dst)     = *reinterpret_cast<u16x8*>(tmp);
      *reinterpret_cast<u16x8*>(dst + 8) = *reinterpret_cast<u16x8*>(tmp + 8);
    }
  } else {
    int idx = (bid - BB * 64) * 256 + threadIdx.x;
    if (idx < MM * HH) {
      int hc = idx >> 8;
      int m  = idx & 255;
      W1T[idx] = f2bf(W1[m * HH + hc]);
    } else {
      int j = idx - MM * HH;
      int m  = j >> 7;
      int hd = j & 127;
      W2T[j] = f2bf(W2[hd * MM + m]);
    }
  }
}

// ---------------- fused main ----------------
// 1024 blocks x 256 threads (4 waves, col-split 64 cols each).
// Block tile 32 rows x 256 cols.
// Phase 1 (k = A@h): NO LDS, NO barriers, no volatile pins — per-lane
// direct-from-global MFMA fragments (A: 32B fp32 + cvtpk (+free rowmax);
// hT: 16B bf16), fully unrolled K-loop; compiler software-pipelines;
// 4 independent blocks/CU (16 waves) provide TLP. A duplicate reads
// across the 4 waves hit L1 (4KB/step working set); hT is L2-resident
// (2MB/XCD via batch swizzle).
// Phases 2/3 + epilogue: identical to round-8 verified code.
// LDS: Kld [32][512B] 16KB; Cld [32][256B] aliases it. -> 4 blocks/CU.
#define KLD 0
#define CLD 0

__global__ __launch_bounds__(256, 4)
void k_fused(const float* __restrict__ Ag, const float* __restrict__ hg,
             const unsigned short* __restrict__ hTg,
             const unsigned short* __restrict__ W1Tg,
             const unsigned short* __restrict__ W2Tg,
             const float* __restrict__ b1g, const float* __restrict__ b2g,
             float* __restrict__ outg) {
  __shared__ __align__(16) char smem[16384];
  __shared__ float smax[32];

  const int tid  = threadIdx.x;
  const int lane = tid & 63;
  const int wid  = tid >> 6;       // 0..3 (col quarter)
  const int l15  = lane & 15;
  const int lg   = lane >> 4;      // 0..3
  const int wcol = wid << 6;       // 0,64,128,192

  const int bid = blockIdx.x;
  const int b   = bid & 31;        // batch-b blocks share bid%8 -> same XCD L2
  const int r0  = (bid >> 5) << 5; // 32 row-blocks of 32

  const float* Ab = Ag + ((size_t)b * NN + r0) * NN;
  const unsigned short* hTb = hTg + (size_t)b * MM * NN;

  // ---- phase 1: barrier-free, LDS-free ----
  f32x4 acc[2][4];
#pragma unroll
  for (int m = 0; m < 2; ++m)
#pragma unroll
    for (int n = 0; n < 4; ++n) acc[m][n] = f32x4{0.f, 0.f, 0.f, 0.f};
  float pm[2] = {-1e30f, -1e30f};

  const float* ap0 = Ab + (size_t)l15 * NN + (lg << 3);         // rows 0..15
  const float* ap1 = Ab + (size_t)(16 + l15) * NN + (lg << 3);  // rows 16..31
  const unsigned short* hp0 = hTb + (size_t)(wcol +  0 + l15) * NN + (lg << 3);
  const unsigned short* hp1 = hTb + (size_t)(wcol + 16 + l15) * NN + (lg << 3);
  const unsigned short* hp2 = hTb + (size_t)(wcol + 32 + l15) * NN + (lg << 3);
  const unsigned short* hp3 = hTb + (size_t)(wcol + 48 + l15) * NN + (lg << 3);

#pragma unroll
  for (int t = 0; t < 32; ++t) {
    const int ko = t << 5;
    float4 a0l = *reinterpret_cast<const float4*>(ap0 + ko);
    float4 a0h = *reinterpret_cast<const float4*>(ap0 + ko + 4);
    float4 a1l = *reinterpret_cast<const float4*>(ap1 + ko);
    float4 a1h = *reinterpret_cast<const float4*>(ap1 + ko + 4);
    bf16x8 bh0 = *reinterpret_cast<const bf16x8*>(hp0 + ko);
    bf16x8 bh1 = *reinterpret_cast<const bf16x8*>(hp1 + ko);
    bf16x8 bh2 = *reinterpret_cast<const bf16x8*>(hp2 + ko);
    bf16x8 bh3 = *reinterpret_cast<const bf16x8*>(hp3 + ko);

    pm[0] = fmaxf(pm[0], fmaxf(fmaxf(fmaxf(a0l.x, a0l.y), fmaxf(a0l.z, a0l.w)),
                               fmaxf(fmaxf(a0h.x, a0h.y), fmaxf(a0h.z, a0h.w))));
    pm[1] = fmaxf(pm[1], fmaxf(fmaxf(fmaxf(a1l.x, a1l.y), fmaxf(a1l.z, a1l.w)),
                               fmaxf(fmaxf(a1h.x, a1h.y), fmaxf(a1h.z, a1h.w))));
    uint4 q0 = make_uint4(cvtpk(a0l.x, a0l.y), cvtpk(a0l.z, a0l.w),
                          cvtpk(a0h.x, a0h.y), cvtpk(a0h.z, a0h.w));
    uint4 q1 = make_uint4(cvtpk(a1l.x, a1l.y), cvtpk(a1l.z, a1l.w),
                          cvtpk(a1h.x, a1h.y), cvtpk(a1h.z, a1h.w));
    bf16x8 af0 = *reinterpret_cast<bf16x8*>(&q0);
    bf16x8 af1 = *reinterpret_cast<bf16x8*>(&q1);

    acc[0][0] = __builtin_amdgcn_mfma_f32_16x16x32_bf16(af0, bh0, acc[0][0], 0, 0, 0);
    acc[1][0] = __builtin_amdgcn_mfma_f32_16x16x32_bf16(af1, bh0, acc[1][0], 0, 0, 0);
    acc[0][1] = __builtin_amdgcn_mfma_f32_16x16x32_bf16(af0, bh1, acc[0][1], 0, 0, 0);
    acc[1][1] = __builtin_amdgcn_mfma_f32_16x16x32_bf16(af1, bh1, acc[1][1], 0, 0, 0);
    acc[0][2] = __builtin_amdgcn_mfma_f32_16x16x32_bf16(af0, bh2, acc[0][2], 0, 0, 0);
    acc[1][2] = __builtin_amdgcn_mfma_f32_16x16x32_bf16(af1, bh2, acc[1][2], 0, 0, 0);
    acc[0][3] = __builtin_amdgcn_mfma_f32_16x16x32_bf16(af0, bh3, acc[0][3], 0, 0, 0);
    acc[1][3] = __builtin_amdgcn_mfma_f32_16x16x32_bf16(af1, bh3, acc[1][3], 0, 0, 0);
  }

  // ---- rowmax finalize: reduce over lg (lane bits 4,5); wave 0 writes ----
  {
    float v0 = pm[0], v1 = pm[1];
    v0 = fmaxf(v0, __shfl_xor(v0, 16));
    v0 = fmaxf(v0, __shfl_xor(v0, 32));
    v1 = fmaxf(v1, __shfl_xor(v1, 16));
    v1 = fmaxf(v1, __shfl_xor(v1, 32));
    if (wid == 0 && lane < 16) {
      smax[lane]      = v0;
      smax[16 + lane] = v1;
    }
  }
  __syncthreads();

  // ---- write k tile (/3, bf16) -> Kld [32][512B] XOR (r8-verified) ----
  {
    const float inv3 = 1.0f / 3.0f;
#pragma unroll
    for (int m = 0; m < 2; ++m)
#pragma unroll
      for (int n = 0; n < 4; ++n) {
        int col = wcol + (n << 4) + l15;
#pragma unroll
        for (int j = 0; j < 4; ++j) {
          int row = (m << 4) + (lg << 2) + j;
          *reinterpret_cast<unsigned short*>(smem + KLD + row * 512 +
                                             ((col * 2) ^ ((row & 7) << 4))) =
              f2bf(acc[m][n][j] * inv3);
        }
      }
  }
  __syncthreads();

  // ---- GEMM1: y[32][128] = k @ W1 (W1T fragments straight from L2) ----
  f32x4 acc1[2][2];
#pragma unroll
  for (int m = 0; m < 2; ++m)
#pragma unroll
    for (int n = 0; n < 2; ++n) acc1[m][n] = f32x4{0.f, 0.f, 0.f, 0.f};
  const int wcol1 = wid << 5;  // 0,32,64,96
#pragma unroll
  for (int kq = 0; kq < 8; ++kq) {
    bf16x8 af[2], bw[2];
#pragma unroll
    for (int m = 0; m < 2; ++m) {
      int row = (m << 4) + l15;
      af[m] = *reinterpret_cast<const bf16x8*>(smem + KLD + row * 512 +
              (((kq * 32 + (lg << 3)) * 2) ^ ((row & 7) << 4)));
    }
#pragma unroll
    for (int n = 0; n < 2; ++n) {
      int col = wcol1 + (n << 4) + l15;
      bw[n] = *reinterpret_cast<const bf16x8*>(W1Tg + (size_t)col * 256 +
                                               kq * 32 + (lg << 3));
    }
#pragma unroll
    for (int m = 0; m < 2; ++m)
#pragma unroll
      for (int n = 0; n < 2; ++n)
        acc1[m][n] = __builtin_amdgcn_mfma_f32_16x16x32_bf16(af[m], bw[n], acc1[m][n], 0, 0, 0);
  }
  __syncthreads();  // done reading Kld; Cld may overwrite

  // ---- c = relu(y+b1) -> Cld [32][256B] XOR (aliases Kld) ----
  {
#pragma unroll
    for (int n = 0; n < 2; ++n) {
      int col = wcol1 + (n << 4) + l15;
      float bias = b1g[col];
#pragma unroll
      for (int m = 0; m < 2; ++m)
#pragma unroll
        for (int j = 0; j < 4; ++j) {
          int row = (m << 4) + (lg << 2) + j;
          float v = fmaxf(acc1[m][n][j] + bias, 0.f);
          *reinterpret_cast<unsigned short*>(smem + CLD + row * 256 +
                                             ((col * 2) ^ ((row & 7) << 4))) = f2bf(v);
        }
    }
  }
  __syncthreads();

  // ---- GEMM2: out2[32][256] = c @ W2 (W2T fragments from L2) ----
  f32x4 acc2[2][4];
#pragma unroll
  for (int m = 0; m < 2; ++m)
#pragma unroll
    for (int n = 0; n < 4; ++n) acc2[m][n] = f32x4{0.f, 0.f, 0.f, 0.f};
#pragma unroll
  for (int kq = 0; kq < 4; ++kq) {
    bf16x8 af[2], bw[4];
#pragma unroll
    for (int m = 0; m < 2; ++m) {
      int row = (m << 4) + l15;
      af[m] = *reinterpret_cast<const bf16x8*>(smem + CLD + row * 256 +
              (((kq * 32 + (lg << 3)) * 2) ^ ((row & 7) << 4)));
    }
#pragma unroll
    for (int n = 0; n < 4; ++n) {
      int col = wcol + (n << 4) + l15;
      bw[n] = *reinterpret_cast<const bf16x8*>(W2Tg + (size_t)col * 128 +
                                               kq * 32 + (lg << 3));
    }
#pragma unroll
    for (int m = 0; m < 2; ++m)
#pragma unroll
      for (int n = 0; n < 4; ++n)
        acc2[m][n] = __builtin_amdgcn_mfma_f32_16x16x32_bf16(af[m], bw[n], acc2[m][n], 0, 0, 0);
  }

  // ---- epilogue: out = (out2+b2)*mask + h*(1-mask) ----
  {
#pragma unroll
    for (int n = 0; n < 4; ++n) {
      int col = wcol + (n << 4) + l15;
      float b2v = b2g[col];
#pragma unroll
      for (int m = 0; m < 2; ++m)
#pragma unroll
        for (int j = 0; j < 4; ++j) {
          int row = (m << 4) + (lg << 2) + j;
          float kv = acc2[m][n][j] + b2v;
          float mask = smax[row];
          size_t gidx = ((size_t)b * NN + r0 + row) * MM + col;
          float hv = hg[gidx];
          outg[gidx] = kv * mask + hv * (1.f - mask);
        }
    }
  }
}

extern "C" void kernel_launch(void* const* d_in, const int* in_sizes, int n_in,
                              void* d_out, int out_size, void* d_ws, size_t ws_size,
                              hipStream_t stream) {
  (void)in_sizes; (void)n_in; (void)out_size; (void)ws_size;
  const float* A  = (const float*)d_in[0];
  const float* h  = (const float*)d_in[1];
  const float* W1 = (const float*)d_in[2];
  const float* b1 = (const float*)d_in[3];
  const float* W2 = (const float*)d_in[4];
  const float* b2 = (const float*)d_in[5];
  float* out = (float*)d_out;

  unsigned short* hT  = (unsigned short*)d_ws;
  unsigned short* W1T = (unsigned short*)((char*)d_ws + (size_t)BB * MM * NN * 2);
  unsigned short* W2T = W1T + MM * HH;

  k_prep<<<BB * 64 + 256, 256, 0, stream>>>(h, hT, W1, W2, W1T, W2T);
  k_fused<<<BB * 32, 256, 0, stream>>>(A, h, hT, W1T, W2T, b1, b2, out);
}

// Round 11
// 146.639 us; speedup vs baseline: 1.0000x; 1.0000x over previous
//
#include <hip/hip_runtime.h>

typedef __attribute__((ext_vector_type(8))) short bf16x8;
typedef __attribute__((ext_vector_type(4))) float f32x4;
typedef __attribute__((ext_vector_type(8))) unsigned short u16x8;

#define BB 32
#define NN 1024
#define MM 256
#define HH 128

__device__ __forceinline__ unsigned short f2bf(float f) {
  union { float f; unsigned int u; } c; c.f = f;
  unsigned int u = c.u + 0x7fffu + ((c.u >> 16) & 1u);  // RNE
  return (unsigned short)(u >> 16);
}
__device__ __forceinline__ unsigned int cvtpk(float lo, float hi) {
  unsigned int r;
  asm("v_cvt_pk_bf16_f32 %0, %1, %2" : "=v"(r) : "v"(lo), "v"(hi));
  return r;
}
// pinned loads: volatile asm keeps program order among volatiles; the
// counted vmcnt + sched_barrier(0) below is the only completion gate.
__device__ __forceinline__ float4 gload_f4(const float* p) {
  float4 r;
  asm volatile("global_load_dwordx4 %0, %1, off" : "=v"(r) : "v"(p));
  return r;
}
__device__ __forceinline__ uint4 gload_u4(const void* p) {
  uint4 r;
  asm volatile("global_load_dwordx4 %0, %1, off" : "=v"(r) : "v"(p));
  return r;
}
#define VMW8() do { asm volatile("s_waitcnt vmcnt(8)" ::: "memory"); \
  __builtin_amdgcn_sched_barrier(0); } while (0)
#define VMW0() do { asm volatile("s_waitcnt vmcnt(0)" ::: "memory"); \
  __builtin_amdgcn_sched_barrier(0); } while (0)

// ---------- combined pre-pass: hT (bf16 [B][M][N]) + W1T/W2T ----------
__global__ __launch_bounds__(256)
void k_prep(const float* __restrict__ hg, unsigned short* __restrict__ hTg,
            const float* __restrict__ W1, const float* __restrict__ W2,
            unsigned short* __restrict__ W1T, unsigned short* __restrict__ W2T) {
  int bid = blockIdx.x;
  if (bid < BB * 64) {
    __shared__ unsigned short tile[64][65];
    int b = bid >> 6;
    int t = bid & 63;
    int k0 = (t >> 2) << 6;
    int m0 = (t & 3) << 6;
    int tt = threadIdx.x;
    {
      int r = tt >> 2;
      int cg = (tt & 3) << 4;
      const float* src = hg + (((size_t)b * NN + k0 + r) * MM + m0 + cg);
#pragma unroll
      for (int i = 0; i < 4; ++i) {
        float4 v = reinterpret_cast<const float4*>(src)[i];
        tile[r][cg + i * 4 + 0] = f2bf(v.x);
        tile[r][cg + i * 4 + 1] = f2bf(v.y);
        tile[r][cg + i * 4 + 2] = f2bf(v.z);
        tile[r][cg + i * 4 + 3] = f2bf(v.w);
      }
    }
    __syncthreads();
    {
      int mr = tt >> 2;
      int kc = (tt & 3) << 4;
      alignas(16) unsigned short tmp[16];
#pragma unroll
      for (int i = 0; i < 16; ++i) tmp[i] = tile[kc + i][mr];
      unsigned short* dst = hTg + (((size_t)b * MM + m0 + mr) * NN + k0 + kc);
      *reinterpret_cast<u16x8*>(dst)     = *reinterpret_cast<u16x8*>(tmp);
      *reinterpret_cast<u16x8*>(dst + 8) = *reinterpret_cast<u16x8*>(tmp + 8);
    }
  } else {
    int idx = (bid - BB * 64) * 256 + threadIdx.x;
    if (idx < MM * HH) {
      int hc = idx >> 8;
      int m  = idx & 255;
      W1T[idx] = f2bf(W1[m * HH + hc]);
    } else {
      int j = idx - MM * HH;
      int m  = j >> 7;
      int hd = j & 127;
      W2T[j] = f2bf(W2[hd * MM + m]);
    }
  }
}

// ---------------- fused main ----------------
// 1024 blocks x 256 threads (4 waves col-split). Block tile 32 rows x 256 cols.
// Phase 1: barrier-free, LDS-free, per-wave independent; ALL loads are
// volatile asm (compiler cannot sink/serialize), explicit 2-step-deep X/Y
// register pipeline, counted s_waitcnt vmcnt(8) (tail vmcnt(0)).
// 3 blocks/CU (launch_bounds(256,3)) = 12 independent waves/CU.
// Phases 2/3 + epilogue: r10-verified code, LDS 16KB (Kld; Cld aliases).
#define KLD 0
#define CLD 0

__global__ __launch_bounds__(256, 3)
void k_fused(const float* __restrict__ Ag, const float* __restrict__ hg,
             const unsigned short* __restrict__ hTg,
             const unsigned short* __restrict__ W1Tg,
             const unsigned short* __restrict__ W2Tg,
             const float* __restrict__ b1g, const float* __restrict__ b2g,
             float* __restrict__ outg) {
  __shared__ __align__(16) char smem[16384];
  __shared__ float smax[32];

  const int tid  = threadIdx.x;
  const int lane = tid & 63;
  const int wid  = tid >> 6;       // 0..3 (col quarter)
  const int l15  = lane & 15;
  const int lg   = lane >> 4;      // 0..3
  const int wcol = wid << 6;       // 0,64,128,192

  const int bid = blockIdx.x;
  const int b   = bid & 31;        // batch-b blocks share bid%8 -> same XCD L2
  const int r0  = (bid >> 5) << 5; // 32 row-blocks of 32

  const float* Ab = Ag + ((size_t)b * NN + r0) * NN;
  const unsigned short* hTb = hTg + (size_t)b * MM * NN;

  f32x4 acc[2][4];
#pragma unroll
  for (int m = 0; m < 2; ++m)
#pragma unroll
    for (int n = 0; n < 4; ++n) acc[m][n] = f32x4{0.f, 0.f, 0.f, 0.f};
  float pm0 = -1e30f, pm1 = -1e30f;

  const float* ap0 = Ab + (size_t)l15 * NN + (lg << 3);         // rows 0..15
  const float* ap1 = Ab + (size_t)(16 + l15) * NN + (lg << 3);  // rows 16..31
  const unsigned short* hp0 = hTb + (size_t)(wcol +  0 + l15) * NN + (lg << 3);
  const unsigned short* hp1 = hTb + (size_t)(wcol + 16 + l15) * NN + (lg << 3);
  const unsigned short* hp2 = hTb + (size_t)(wcol + 32 + l15) * NN + (lg << 3);
  const unsigned short* hp3 = hTb + (size_t)(wcol + 48 + l15) * NN + (lg << 3);

  // X / Y staging register sets (named scalars; no arrays -> no dyn indexing)
  float4 xa0l, xa0h, xa1l, xa1h;  uint4 xh0, xh1, xh2, xh3;
  float4 ya0l, ya0h, ya1l, ya1h;  uint4 yh0, yh1, yh2, yh3;

#define ISSUE_X(KO)                                                          \
  do {                                                                       \
    xa0l = gload_f4(ap0 + (KO));      xa0h = gload_f4(ap0 + (KO) + 4);       \
    xa1l = gload_f4(ap1 + (KO));      xa1h = gload_f4(ap1 + (KO) + 4);       \
    xh0 = gload_u4(hp0 + (KO));       xh1 = gload_u4(hp1 + (KO));            \
    xh2 = gload_u4(hp2 + (KO));       xh3 = gload_u4(hp3 + (KO));            \
  } while (0)
#define ISSUE_Y(KO)                                                          \
  do {                                                                       \
    ya0l = gload_f4(ap0 + (KO));      ya0h = gload_f4(ap0 + (KO) + 4);       \
    ya1l = gload_f4(ap1 + (KO));      ya1h = gload_f4(ap1 + (KO) + 4);       \
    yh0 = gload_u4(hp0 + (KO));       yh1 = gload_u4(hp1 + (KO));            \
    yh2 = gload_u4(hp2 + (KO));       yh3 = gload_u4(hp3 + (KO));            \
  } while (0)

#define CONSUME(A0L, A0H, A1L, A1H, H0, H1, H2, H3)                          \
  do {                                                                       \
    pm0 = fmaxf(pm0, fmaxf(fmaxf(fmaxf((A0L).x, (A0L).y), fmaxf((A0L).z, (A0L).w)), \
                           fmaxf(fmaxf((A0H).x, (A0H).y), fmaxf((A0H).z, (A0H).w)))); \
    pm1 = fmaxf(pm1, fmaxf(fmaxf(fmaxf((A1L).x, (A1L).y), fmaxf((A1L).z, (A1L).w)), \
                           fmaxf(fmaxf((A1H).x, (A1H).y), fmaxf((A1H).z, (A1H).w)))); \
    uint4 q0 = make_uint4(cvtpk((A0L).x, (A0L).y), cvtpk((A0L).z, (A0L).w),  \
                          cvtpk((A0H).x, (A0H).y), cvtpk((A0H).z, (A0H).w)); \
    uint4 q1 = make_uint4(cvtpk((A1L).x, (A1L).y), cvtpk((A1L).z, (A1L).w),  \
                          cvtpk((A1H).x, (A1H).y), cvtpk((A1H).z, (A1H).w)); \
    bf16x8 af0 = *reinterpret_cast<bf16x8*>(&q0);                            \
    bf16x8 af1 = *reinterpret_cast<bf16x8*>(&q1);                            \
    bf16x8 b0 = *reinterpret_cast<bf16x8*>(&(H0));                           \
    bf16x8 b1 = *reinterpret_cast<bf16x8*>(&(H1));                           \
    bf16x8 b2 = *reinterpret_cast<bf16x8*>(&(H2));                           \
    bf16x8 b3 = *reinterpret_cast<bf16x8*>(&(H3));                           \
    acc[0][0] = __builtin_amdgcn_mfma_f32_16x16x32_bf16(af0, b0, acc[0][0], 0, 0, 0); \
    acc[1][0] = __builtin_amdgcn_mfma_f32_16x16x32_bf16(af1, b0, acc[1][0], 0, 0, 0); \
    acc[0][1] = __builtin_amdgcn_mfma_f32_16x16x32_bf16(af0, b1, acc[0][1], 0, 0, 0); \
    acc[1][1] = __builtin_amdgcn_mfma_f32_16x16x32_bf16(af1, b1, acc[1][1], 0, 0, 0); \
    acc[0][2] = __builtin_amdgcn_mfma_f32_16x16x32_bf16(af0, b2, acc[0][2], 0, 0, 0); \
    acc[1][2] = __builtin_amdgcn_mfma_f32_16x16x32_bf16(af1, b2, acc[1][2], 0, 0, 0); \
    acc[0][3] = __builtin_amdgcn_mfma_f32_16x16x32_bf16(af0, b3, acc[0][3], 0, 0, 0); \
    acc[1][3] = __builtin_amdgcn_mfma_f32_16x16x32_bf16(af1, b3, acc[1][3], 0, 0, 0); \
  } while (0)

  // ---- phase 1: 32 K-steps of 32, 2-deep X/Y pipeline, zero barriers ----
  ISSUE_X(0);
  ISSUE_Y(32);
#pragma unroll
  for (int t2 = 0; t2 < 16; ++t2) {
    VMW8();                       // X (oldest 8) landed; Y in flight
    CONSUME(xa0l, xa0h, xa1l, xa1h, xh0, xh1, xh2, xh3);
    if (t2 < 15) ISSUE_X((2 * t2 + 2) << 5);
    if (t2 < 15) VMW8(); else VMW0();   // Y landed; X' in flight
    CONSUME(ya0l, ya0h, ya1l, ya1h, yh0, yh1, yh2, yh3);
    if (t2 < 15) ISSUE_Y((2 * t2 + 3) << 5);
  }

  // ---- rowmax finalize: reduce over lg (lane bits 4,5); wave 0 writes ----
  {
    float v0 = pm0, v1 = pm1;
    v0 = fmaxf(v0, __shfl_xor(v0, 16));
    v0 = fmaxf(v0, __shfl_xor(v0, 32));
    v1 = fmaxf(v1, __shfl_xor(v1, 16));
    v1 = fmaxf(v1, __shfl_xor(v1, 32));
    if (wid == 0 && lane < 16) {
      smax[lane]      = v0;
      smax[16 + lane] = v1;
    }
  }
  __syncthreads();

  // ---- write k tile (/3, bf16) -> Kld [32][512B] XOR (verified) ----
  {
    const float inv3 = 1.0f / 3.0f;
#pragma unroll
    for (int m = 0; m < 2; ++m)
#pragma unroll
      for (int n = 0; n < 4; ++n) {
        int col = wcol + (n << 4) + l15;
#pragma unroll
        for (int j = 0; j < 4; ++j) {
          int row = (m << 4) + (lg << 2) + j;
          *reinterpret_cast<unsigned short*>(smem + KLD + row * 512 +
                                             ((col * 2) ^ ((row & 7) << 4))) =
              f2bf(acc[m][n][j] * inv3);
        }
      }
  }
  __syncthreads();

  // ---- GEMM1: y[32][128] = k @ W1 (W1T fragments straight from L2) ----
  f32x4 acc1[2][2];
#pragma unroll
  for (int m = 0; m < 2; ++m)
#pragma unroll
    for (int n = 0; n < 2; ++n) acc1[m][n] = f32x4{0.f, 0.f, 0.f, 0.f};
  const int wcol1 = wid << 5;  // 0,32,64,96
#pragma unroll
  for (int kq = 0; kq < 8; ++kq) {
    bf16x8 af[2], bw[2];
#pragma unroll
    for (int m = 0; m < 2; ++m) {
      int row = (m << 4) + l15;
      af[m] = *reinterpret_cast<const bf16x8*>(smem + KLD + row * 512 +
              (((kq * 32 + (lg << 3)) * 2) ^ ((row & 7) << 4)));
    }
#pragma unroll
    for (int n = 0; n < 2; ++n) {
      int col = wcol1 + (n << 4) + l15;
      bw[n] = *reinterpret_cast<const bf16x8*>(W1Tg + (size_t)col * 256 +
                                               kq * 32 + (lg << 3));
    }
#pragma unroll
    for (int m = 0; m < 2; ++m)
#pragma unroll
      for (int n = 0; n < 2; ++n)
        acc1[m][n] = __builtin_amdgcn_mfma_f32_16x16x32_bf16(af[m], bw[n], acc1[m][n], 0, 0, 0);
  }
  __syncthreads();  // done reading Kld; Cld may overwrite

  // ---- c = relu(y+b1) -> Cld [32][256B] XOR (aliases Kld) ----
  {
#pragma unroll
    for (int n = 0; n < 2; ++n) {
      int col = wcol1 + (n << 4) + l15;
      float bias = b1g[col];
#pragma unroll
      for (int m = 0; m < 2; ++m)
#pragma unroll
        for (int j = 0; j < 4; ++j) {
          int row = (m << 4) + (lg << 2) + j;
          float v = fmaxf(acc1[m][n][j] + bias, 0.f);
          *reinterpret_cast<unsigned short*>(smem + CLD + row * 256 +
                                             ((col * 2) ^ ((row & 7) << 4))) = f2bf(v);
        }
    }
  }
  __syncthreads();

  // ---- GEMM2: out2[32][256] = c @ W2 (W2T fragments from L2) ----
  f32x4 acc2[2][4];
#pragma unroll
  for (int m = 0; m < 2; ++m)
#pragma unroll
    for (int n = 0; n < 4; ++n) acc2[m][n] = f32x4{0.f, 0.f, 0.f, 0.f};
#pragma unroll
  for (int kq = 0; kq < 4; ++kq) {
    bf16x8 af[2], bw[4];
#pragma unroll
    for (int m = 0; m < 2; ++m) {
      int row = (m << 4) + l15;
      af[m] = *reinterpret_cast<const bf16x8*>(smem + CLD + row * 256 +
              (((kq * 32 + (lg << 3)) * 2) ^ ((row & 7) << 4)));
    }
#pragma unroll
    for (int n = 0; n < 4; ++n) {
      int col = wcol + (n << 4) + l15;
      bw[n] = *reinterpret_cast<const bf16x8*>(W2Tg + (size_t)col * 128 +
                                               kq * 32 + (lg << 3));
    }
#pragma unroll
    for (int m = 0; m < 2; ++m)
#pragma unroll
      for (int n = 0; n < 4; ++n)
        acc2[m][n] = __builtin_amdgcn_mfma_f32_16x16x32_bf16(af[m], bw[n], acc2[m][n], 0, 0, 0);
  }

  // ---- epilogue: out = (out2+b2)*mask + h*(1-mask) ----
  {
#pragma unroll
    for (int n = 0; n < 4; ++n) {
      int col = wcol + (n << 4) + l15;
      float b2v = b2g[col];
#pragma unroll
      for (int m = 0; m < 2; ++m)
#pragma unroll
        for (int j = 0; j < 4; ++j) {
          int row = (m << 4) + (lg << 2) + j;
          float kv = acc2[m][n][j] + b2v;
          float mask = smax[row];
          size_t gidx = ((size_t)b * NN + r0 + row) * MM + col;
          float hv = hg[gidx];
          outg[gidx] = kv * mask + hv * (1.f - mask);
        }
    }
  }
#undef CONSUME
#undef ISSUE_X
#undef ISSUE_Y
}

extern "C" void kernel_launch(void* const* d_in, const int* in_sizes, int n_in,
                              void* d_out, int out_size, void* d_ws, size_t ws_size,
                              hipStream_t stream) {
  (void)in_sizes; (void)n_in; (void)out_size; (void)ws_size;
  const float* A  = (const float*)d_in[0];
  const float* h  = (const float*)d_in[1];
  const float* W1 = (const float*)d_in[2];
  const float* b1 = (const float*)d_in[3];
  const float* W2 = (const float*)d_in[4];
  const float* b2 = (const float*)d_in[5];
  float* out = (float*)d_out;

  unsigned short* hT  = (unsigned short*)d_ws;
  unsigned short* W1T = (unsigned short*)((char*)d_ws + (size_t)BB * MM * NN * 2);
  unsigned short* W2T = W1T + MM * HH;

  k_prep<<<BB * 64 + 256, 256, 0, stream>>>(h, hT, W1, W2, W1T, W2T);
  k_fused<<<BB * 32, 256, 0, stream>>>(A, h, hT, W1T, W2T, b1, b2, out);
}

// Round 12
// 139.846 us; speedup vs baseline: 1.0486x; 1.0486x over previous
//
#include <hip/hip_runtime.h>

typedef __attribute__((ext_vector_type(8))) short bf16x8;
typedef __attribute__((ext_vector_type(4))) float f32x4;
typedef __attribute__((ext_vector_type(8))) unsigned short u16x8;

#define BB 32
#define NN 1024
#define MM 256
#define HH 128

__device__ __forceinline__ unsigned short f2bf(float f) {
  union { float f; unsigned int u; } c; c.f = f;
  unsigned int u = c.u + 0x7fffu + ((c.u >> 16) & 1u);  // RNE
  return (unsigned short)(u >> 16);
}
__device__ __forceinline__ unsigned int cvtpk(float lo, float hi) {
  unsigned int r;
  asm("v_cvt_pk_bf16_f32 %0, %1, %2" : "=v"(r) : "v"(lo), "v"(hi));
  return r;
}
__device__ __forceinline__ float4 gload_f4(const float* p) {
  float4 r;
  asm volatile("global_load_dwordx4 %0, %1, off" : "=v"(r) : "v"(p));
  return r;
}
typedef __attribute__((address_space(3))) unsigned int as3_u32;
typedef const __attribute__((address_space(1))) unsigned int as1_u32;
__device__ __forceinline__ void gl_lds16(const void* g, void* l) {
  __builtin_amdgcn_global_load_lds((as1_u32*)g, (as3_u32*)l, 16, 0, 0);
}

// ---------- combined pre-pass: hT (bf16 [B][M][N]) + W1T/W2T ----------
__global__ __launch_bounds__(256)
void k_prep(const float* __restrict__ hg, unsigned short* __restrict__ hTg,
            const float* __restrict__ W1, const float* __restrict__ W2,
            unsigned short* __restrict__ W1T, unsigned short* __restrict__ W2T) {
  int bid = blockIdx.x;
  if (bid < BB * 64) {
    __shared__ unsigned short tile[64][65];
    int b = bid >> 6;
    int t = bid & 63;
    int k0 = (t >> 2) << 6;
    int m0 = (t & 3) << 6;
    int tt = threadIdx.x;
    {
      int r = tt >> 2;
      int cg = (tt & 3) << 4;
      const float* src = hg + (((size_t)b * NN + k0 + r) * MM + m0 + cg);
#pragma unroll
      for (int i = 0; i < 4; ++i) {
        float4 v = reinterpret_cast<const float4*>(src)[i];
        tile[r][cg + i * 4 + 0] = f2bf(v.x);
        tile[r][cg + i * 4 + 1] = f2bf(v.y);
        tile[r][cg + i * 4 + 2] = f2bf(v.z);
        tile[r][cg + i * 4 + 3] = f2bf(v.w);
      }
    }
    __syncthreads();
    {
      int mr = tt >> 2;
      int kc = (tt & 3) << 4;
      alignas(16) unsigned short tmp[16];
#pragma unroll
      for (int i = 0; i < 16; ++i) tmp[i] = tile[kc + i][mr];
      unsigned short* dst = hTg + (((size_t)b * MM + m0 + mr) * NN + k0 + kc);
      *reinterpret_cast<u16x8*>(dst)     = *reinterpret_cast<u16x8*>(tmp);
      *reinterpret_cast<u16x8*>(dst + 8) = *reinterpret_cast<u16x8*>(tmp + 8);
    }
  } else {
    int idx = (bid - BB * 64) * 256 + threadIdx.x;
    if (idx < MM * HH) {
      int hc = idx >> 8;
      int m  = idx & 255;
      W1T[idx] = f2bf(W1[m * HH + hc]);
    } else {
      int j = idx - MM * HH;
      int m  = j >> 7;
      int hd = j & 127;
      W2T[j] = f2bf(W2[hd * MM + m]);
    }
  }
}

// ---------------- fused main ----------------
// 256 blocks x 512 threads (8 waves 2x4). Block tile 128 x 256, BK=32.
// LDS 64KB -> 2 blocks/CU (16 waves, 2 independent barrier groups).
//   A bf16 dbuf: [128 rows][64B], 16B-slot XOR ^(row&3)  -> 2 x 8KB  @0,8K
//   H bf16 dbuf: [256 cols][64B], 16B-slot XOR ^(col&3)  -> 2 x 16KB @16K,32K
//   (both read/write patterns hit 8 distinct 4-bank groups x 8 lanes: free)
//   Kld [128][512B] 64KB aliases all; Cld [128][256B] 32KB aliases Kld.
// Per step t: issue H(t+1) gl_lds (oldest) -> issue A(t+2) pinned regs ->
//   CONSUME(t) -> vmcnt(2) [H landed, A(t+2) STILL IN FLIGHT] ->
//   cvt A(t+1)->LDS -> lgkmcnt(0); s_barrier.   One barrier/step.
#define AB_(x) ((x) * 8192)
#define HB_(x) (16384 + (x) * 16384)
#define KLD 0
#define CLD 0

#define PIPE_BARRIER() do { \
  asm volatile("s_waitcnt lgkmcnt(0)" ::: "memory"); \
  __builtin_amdgcn_s_barrier(); \
  asm volatile("" ::: "memory"); } while (0)
#define VMW(N) do { asm volatile("s_waitcnt vmcnt(" #N ")" ::: "memory"); \
  __builtin_amdgcn_sched_barrier(0); } while (0)

__global__ __launch_bounds__(512, 4)
void k_fused(const float* __restrict__ Ag, const float* __restrict__ hg,
             const unsigned short* __restrict__ hTg,
             const unsigned short* __restrict__ W1Tg,
             const unsigned short* __restrict__ W2Tg,
             const float* __restrict__ b1g, const float* __restrict__ b2g,
             float* __restrict__ outg) {
  __shared__ __align__(16) char smem[65536];
  __shared__ float smax[128];

  const int tid  = threadIdx.x;
  const int lane = tid & 63;
  const int wid  = tid >> 6;       // 0..7
  const int wr   = wid >> 2;       // 0..1 row half
  const int wc   = wid & 3;        // 0..3 col quarter
  const int l15  = lane & 15;
  const int lg   = lane >> 4;      // 0..3

  const int bid = blockIdx.x;
  const int b   = bid & 31;        // batch-b blocks share bid%8 -> same XCD L2
  const int r0  = (bid >> 5) << 7; // 8 row-blocks of 128

  const float* Ab = Ag + ((size_t)b * NN + r0) * NN;
  const unsigned short* hTb = hTg + (size_t)b * MM * NN;

  // ---- A staging: thread -> (row=tid>>2, 8 floats at 8*(tid&3)) ----
  const int arow = tid >> 2;           // 0..127
  const int ass  = tid & 3;            // 16B bf16 slot after cvt
  const float* Asrc = Ab + (size_t)arow * NN + (ass << 3);
  const int awb = arow * 64 + ((ass << 4) ^ ((arow & 3) << 4));  // LDS byte

  // ---- H staging: chunk c in [0,1024): col=c>>2, slot=c&3 (16B) ----
  // src pre-swizzled (rule 21): slot ss holds source slot ss^(col&3)
  const unsigned short* baseH[2];
  {
    int c0 = tid;
    baseH[0] = hTb + (size_t)(c0 >> 2) * NN + (((c0 & 3) ^ ((c0 >> 2) & 3)) << 3);
    int c1 = tid + 512;
    baseH[1] = hTb + (size_t)(c1 >> 2) * NN + (((c1 & 3) ^ ((c1 >> 2) & 3)) << 3);
  }
  const int dstW = wid << 10;          // wave-uniform 1KB chunk base

#define STAGE_H(K0, HB)                                                      \
  do {                                                                       \
    gl_lds16(baseH[0] + (K0), smem + (HB) + dstW);                           \
    gl_lds16(baseH[1] + (K0), smem + (HB) + 8192 + dstW);                    \
  } while (0)

  float4 xa0, xa1, ya0, ya1;   // X = A(odd t), Y = A(even t): 8 VGPR each
#define ISSUE_AX(K0) do { xa0 = gload_f4(Asrc + (K0)); \
                          xa1 = gload_f4(Asrc + (K0) + 4); } while (0)
#define ISSUE_AY(K0) do { ya0 = gload_f4(Asrc + (K0)); \
                          ya1 = gload_f4(Asrc + (K0) + 4); } while (0)

  float pmax = -1e30f;
#define CVTWR(AB, R0, R1)                                                    \
  do {                                                                       \
    pmax = fmaxf(pmax, fmaxf(fmaxf(fmaxf((R0).x, (R0).y), fmaxf((R0).z, (R0).w)), \
                             fmaxf(fmaxf((R1).x, (R1).y), fmaxf((R1).z, (R1).w)))); \
    uint2 q = make_uint2(cvtpk((R0).x, (R0).y), cvtpk((R0).z, (R0).w));      \
    uint2 q2 = make_uint2(cvtpk((R1).x, (R1).y), cvtpk((R1).z, (R1).w));     \
    *reinterpret_cast<uint2*>(smem + (AB) + awb)     = q;                    \
    *reinterpret_cast<uint2*>(smem + (AB) + awb + 8) = q2;                   \
  } while (0)

  f32x4 acc[4][4];
#pragma unroll
  for (int m = 0; m < 4; ++m)
#pragma unroll
    for (int n = 0; n < 4; ++n) acc[m][n] = f32x4{0.f, 0.f, 0.f, 0.f};

#define CONSUME(AB, HB)                                                      \
  do {                                                                       \
    bf16x8 af[4], bh[4];                                                     \
    _Pragma("unroll")                                                        \
    for (int m = 0; m < 4; ++m) {                                            \
      int row = (wr << 6) + (m << 4) + l15;                                  \
      af[m] = *reinterpret_cast<const bf16x8*>(                              \
          smem + (AB) + row * 64 + ((lg << 4) ^ ((row & 3) << 4)));          \
    }                                                                        \
    _Pragma("unroll")                                                        \
    for (int n = 0; n < 4; ++n) {                                            \
      int col = (wc << 6) + (n << 4) + l15;                                  \
      bh[n] = *reinterpret_cast<const bf16x8*>(                              \
          smem + (HB) + col * 64 + ((lg << 4) ^ ((col & 3) << 4)));          \
    }                                                                        \
    _Pragma("unroll")                                                        \
    for (int m = 0; m < 4; ++m)                                              \
      _Pragma("unroll")                                                      \
      for (int n = 0; n < 4; ++n)                                            \
        acc[m][n] = __builtin_amdgcn_mfma_f32_16x16x32_bf16(af[m], bh[n],    \
                                                            acc[m][n], 0, 0, 0); \
  } while (0)

  // ---- prologue: stage step 0; A(1) issued into X ----
  STAGE_H(0, HB_(0));
  ISSUE_AY(0);
  VMW(0);
  CVTWR(AB_(0), ya0, ya1);
  ISSUE_AX(32);                  // A(1) -> X
  PIPE_BARRIER();

  // ---- phase 1: 32 K-steps of 32, one barrier/step, counted waits ----
#pragma unroll
  for (int t2 = 0; t2 < 16; ++t2) {
    const int te = 2 * t2;       // even step
    // even step te: consume buf0; cvt X=A(te+1); issue A(te+2)->Y
    if (te < 31) STAGE_H((te + 1) * 32, HB_(1));
    if (te < 30) ISSUE_AY((te + 2) * 32);
    CONSUME(AB_(0), HB_(0));
    if (te < 31) {
      if (te < 30) VMW(2); else VMW(0);
      CVTWR(AB_(1), xa0, xa1);
      PIPE_BARRIER();
    }
    // odd step to = te+1: consume buf1; cvt Y=A(to+1); issue A(to+2)->X
    const int to = te + 1;
    if (to < 31) STAGE_H((to + 1) * 32, HB_(0));
    if (to < 30) ISSUE_AX((to + 2) * 32);
    CONSUME(AB_(1), HB_(1));
    if (to < 31) {
      if (to < 30) VMW(2); else VMW(0);
      CVTWR(AB_(0), ya0, ya1);
      PIPE_BARRIER();
    }
  }

  // ---- rowmax finalize (4 staging threads per row are adjacent lanes) ----
  {
    float v = pmax;
    v = fmaxf(v, __shfl_xor(v, 1));
    v = fmaxf(v, __shfl_xor(v, 2));
    if ((tid & 3) == 0) smax[arow] = v;
  }
  __syncthreads();   // phase-1 LDS fully retired before aliasing

  // ---- write k tile (/3, bf16) -> Kld [128][512B] XOR (r7-verified) ----
  {
    const float inv3 = 1.0f / 3.0f;
#pragma unroll
    for (int m = 0; m < 4; ++m)
#pragma unroll
      for (int n = 0; n < 4; ++n) {
        int col = (wc << 6) + (n << 4) + l15;
#pragma unroll
        for (int j = 0; j < 4; ++j) {
          int row = (wr << 6) + (m << 4) + (lg << 2) + j;
          *reinterpret_cast<unsigned short*>(smem + KLD + row * 512 +
                                             ((col * 2) ^ ((row & 7) << 4))) =
              f2bf(acc[m][n][j] * inv3);
        }
      }
  }
  __syncthreads();

  // ---- GEMM1: y[128][128] = k @ W1 (W1T fragments straight from L2) ----
  f32x4 acc1[4][2];
#pragma unroll
  for (int m = 0; m < 4; ++m)
#pragma unroll
    for (int n = 0; n < 2; ++n) acc1[m][n] = f32x4{0.f, 0.f, 0.f, 0.f};
  const int wcol1 = wc << 5;  // 0,32,64,96
#pragma unroll
  for (int kq = 0; kq < 8; ++kq) {
    bf16x8 af[4], bw[2];
#pragma unroll
    for (int m = 0; m < 4; ++m) {
      int row = (wr << 6) + (m << 4) + l15;
      af[m] = *reinterpret_cast<const bf16x8*>(smem + KLD + row * 512 +
              (((kq * 32 + (lg << 3)) * 2) ^ ((row & 7) << 4)));
    }
#pragma unroll
    for (int n = 0; n < 2; ++n) {
      int col = wcol1 + (n << 4) + l15;
      bw[n] = *reinterpret_cast<const bf16x8*>(W1Tg + (size_t)col * 256 +
                                               kq * 32 + (lg << 3));
    }
#pragma unroll
    for (int m = 0; m < 4; ++m)
#pragma unroll
      for (int n = 0; n < 2; ++n)
        acc1[m][n] = __builtin_amdgcn_mfma_f32_16x16x32_bf16(af[m], bw[n], acc1[m][n], 0, 0, 0);
  }
  __syncthreads();  // Kld fully read; Cld may overwrite

  // ---- c = relu(y+b1) -> Cld [128][256B] XOR ----
  {
#pragma unroll
    for (int n = 0; n < 2; ++n) {
      int col = wcol1 + (n << 4) + l15;
      float bias = b1g[col];
#pragma unroll
      for (int m = 0; m < 4; ++m)
#pragma unroll
        for (int j = 0; j < 4; ++j) {
          int row = (wr << 6) + (m << 4) + (lg << 2) + j;
          float v = fmaxf(acc1[m][n][j] + bias, 0.f);
          *reinterpret_cast<unsigned short*>(smem + CLD + row * 256 +
                                             ((col * 2) ^ ((row & 7) << 4))) = f2bf(v);
        }
    }
  }
  __syncthreads();

  // ---- GEMM2: out2[128][256] = c @ W2 (W2T fragments from L2) ----
  f32x4 acc2[4][4];
#pragma unroll
  for (int m = 0; m < 4; ++m)
#pragma unroll
    for (int n = 0; n < 4; ++n) acc2[m][n] = f32x4{0.f, 0.f, 0.f, 0.f};
#pragma unroll
  for (int kq = 0; kq < 4; ++kq) {
    bf16x8 af[4], bw[4];
#pragma unroll
    for (int m = 0; m < 4; ++m) {
      int row = (wr << 6) + (m << 4) + l15;
      af[m] = *reinterpret_cast<const bf16x8*>(smem + CLD + row * 256 +
              (((kq * 32 + (lg << 3)) * 2) ^ ((row & 7) << 4)));
    }
#pragma unroll
    for (int n = 0; n < 4; ++n) {
      int col = (wc << 6) + (n << 4) + l15;
      bw[n] = *reinterpret_cast<const bf16x8*>(W2Tg + (size_t)col * 128 +
                                               kq * 32 + (lg << 3));
    }
#pragma unroll
    for (int m = 0; m < 4; ++m)
#pragma unroll
      for (int n = 0; n < 4; ++n)
        acc2[m][n] = __builtin_amdgcn_mfma_f32_16x16x32_bf16(af[m], bw[n], acc2[m][n], 0, 0, 0);
  }

  // ---- epilogue: out = (out2+b2)*mask + h*(1-mask) ----
  {
#pragma unroll
    for (int n = 0; n < 4; ++n) {
      int col = (wc << 6) + (n << 4) + l15;
      float b2v = b2g[col];
#pragma unroll
      for (int m = 0; m < 4; ++m)
#pragma unroll
        for (int j = 0; j < 4; ++j) {
          int row = (wr << 6) + (m << 4) + (lg << 2) + j;
          float kv = acc2[m][n][j] + b2v;
          float mask = smax[row];
          size_t gidx = ((size_t)b * NN + r0 + row) * MM + col;
          float hv = hg[gidx];
          outg[gidx] = kv * mask + hv * (1.f - mask);
        }
    }
  }
#undef CONSUME
#undef CVTWR
#undef ISSUE_AX
#undef ISSUE_AY
#undef STAGE_H
}

extern "C" void kernel_launch(void* const* d_in, const int* in_sizes, int n_in,
                              void* d_out, int out_size, void* d_ws, size_t ws_size,
                              hipStream_t stream) {
  (void)in_sizes; (void)n_in; (void)out_size; (void)ws_size;
  const float* A  = (const float*)d_in[0];
  const float* h  = (const float*)d_in[1];
  const float* W1 = (const float*)d_in[2];
  const float* b1 = (const float*)d_in[3];
  const float* W2 = (const float*)d_in[4];
  const float* b2 = (const float*)d_in[5];
  float* out = (float*)d_out;

  unsigned short* hT  = (unsigned short*)d_ws;
  unsigned short* W1T = (unsigned short*)((char*)d_ws + (size_t)BB * MM * NN * 2);
  unsigned short* W2T = W1T + MM * HH;

  k_prep<<<BB * 64 + 256, 256, 0, stream>>>(h, hT, W1, W2, W1T, W2T);
  k_fused<<<BB * 8, 512, 0, stream>>>(A, h, hT, W1T, W2T, b1, b2, out);
}

// Round 14
// 104.138 us; speedup vs baseline: 1.4081x; 1.3429x over previous
//
#include <hip/hip_runtime.h>

typedef __attribute__((ext_vector_type(8))) short bf16x8;
typedef __attribute__((ext_vector_type(4))) float f32x4;
typedef __attribute__((ext_vector_type(8))) unsigned short u16x8;

#define BB 32
#define NN 1024
#define MM 256
#define HH 128

__device__ __forceinline__ unsigned short f2bf(float f) {
  union { float f; unsigned int u; } c; c.f = f;
  unsigned int u = c.u + 0x7fffu + ((c.u >> 16) & 1u);  // RNE
  return (unsigned short)(u >> 16);
}
__device__ __forceinline__ unsigned int cvtpk(float lo, float hi) {
  unsigned int r;
  asm("v_cvt_pk_bf16_f32 %0, %1, %2" : "=v"(r) : "v"(lo), "v"(hi));
  return r;
}
__device__ __forceinline__ float4 gload_f4(const float* p) {
  float4 r;
  asm volatile("global_load_dwordx4 %0, %1, off" : "=v"(r) : "v"(p));
  return r;
}
typedef __attribute__((address_space(3))) unsigned int as3_u32;
typedef const __attribute__((address_space(1))) unsigned int as1_u32;
__device__ __forceinline__ void gl_lds16(const void* g, void* l) {
  __builtin_amdgcn_global_load_lds((as1_u32*)g, (as3_u32*)l, 16, 0, 0);
}

// ---------- combined pre-pass: hT (bf16 [B][M][N]) + W1T/W2T ----------
__global__ __launch_bounds__(256)
void k_prep(const float* __restrict__ hg, unsigned short* __restrict__ hTg,
            const float* __restrict__ W1, const float* __restrict__ W2,
            unsigned short* __restrict__ W1T, unsigned short* __restrict__ W2T) {
  int bid = blockIdx.x;
  if (bid < BB * 64) {
    __shared__ unsigned short tile[64][65];
    int b = bid >> 6;
    int t = bid & 63;
    int k0 = (t >> 2) << 6;
    int m0 = (t & 3) << 6;
    int tt = threadIdx.x;
    {
      int r = tt >> 2;
      int cg = (tt & 3) << 4;
      const float* src = hg + (((size_t)b * NN + k0 + r) * MM + m0 + cg);
#pragma unroll
      for (int i = 0; i < 4; ++i) {
        float4 v = reinterpret_cast<const float4*>(src)[i];
        tile[r][cg + i * 4 + 0] = f2bf(v.x);
        tile[r][cg + i * 4 + 1] = f2bf(v.y);
        tile[r][cg + i * 4 + 2] = f2bf(v.z);
        tile[r][cg + i * 4 + 3] = f2bf(v.w);
      }
    }
    __syncthreads();
    {
      int mr = tt >> 2;
      int kc = (tt & 3) << 4;
      alignas(16) unsigned short tmp[16];
#pragma unroll
      for (int i = 0; i < 16; ++i) tmp[i] = tile[kc + i][mr];
      unsigned short* dst = hTg + (((size_t)b * MM + m0 + mr) * NN + k0 + kc);
      *reinterpret_cast<u16x8*>(dst)     = *reinterpret_cast<u16x8*>(tmp);
      *reinterpret_cast<u16x8*>(dst + 8) = *reinterpret_cast<u16x8*>(tmp + 8);
    }
  } else {
    int idx = (bid - BB * 64) * 256 + threadIdx.x;
    if (idx < MM * HH) {
      int hc = idx >> 8;
      int m  = idx & 255;
      W1T[idx] = f2bf(W1[m * HH + hc]);
    } else {
      int j = idx - MM * HH;
      int m  = j >> 7;
      int hd = j & 127;
      W2T[j] = f2bf(W2[hd * MM + m]);
    }
  }
}

// ---------------- fused main ----------------
// 512 blocks x 512 threads (8 waves = 2 row-halves x 4 col-quarters).
// Block tile 64 rows x 256 cols; per-wave 32x64; BK=64, 16 K-steps.
// A: DIRECT per-lane fragment loads (asm-volatile-pinned, 1 step ahead;
//    vmcnt(0) AT POINT OF USE — the r13 bug was omitting this wait).
// H: r7-verified gl_lds dbuf [256 cols][128B] ^(col&7)<<4, pre-swizzled src.
// Per step t: vmcnt(0)[A(t) regs landed] -> cvt A(t) -> issue H(t+1) gl_lds
//   + A(t+1) pinned -> consume -> vmcnt(8) [H(t+1) in LDS, A(t+1) crosses
//   the barrier in flight] -> lgkm-barrier. One barrier/step.
// LDS = 64KB H dbuf only -> 2 blocks/CU (launch_bounds caps VGPR at 128).
// Kld [64][512B]=32KB aliases HB0; Cld [64][256B]=16KB at +32K.
#define HB_(x) ((x) * 32768)
#define KLD 0
#define CLD 32768

#define PIPE_BARRIER() do { \
  asm volatile("s_waitcnt lgkmcnt(0)" ::: "memory"); \
  __builtin_amdgcn_s_barrier(); \
  asm volatile("" ::: "memory"); } while (0)
#define VMW(N) do { asm volatile("s_waitcnt vmcnt(" #N ")" ::: "memory"); \
  __builtin_amdgcn_sched_barrier(0); } while (0)

__global__ __launch_bounds__(512, 4)
void k_fused(const float* __restrict__ Ag, const float* __restrict__ hg,
             const unsigned short* __restrict__ hTg,
             const unsigned short* __restrict__ W1Tg,
             const unsigned short* __restrict__ W2Tg,
             const float* __restrict__ b1g, const float* __restrict__ b2g,
             float* __restrict__ outg) {
  __shared__ __align__(16) char smem[65536];
  __shared__ float smax[64];

  const int tid  = threadIdx.x;
  const int lane = tid & 63;
  const int wid  = tid >> 6;       // 0..7
  const int wr   = wid >> 2;       // 0..1 row half (32 rows)
  const int wc   = wid & 3;        // 0..3 col quarter (64 cols)
  const int l15  = lane & 15;
  const int lg   = lane >> 4;      // 0..3

  const int bid = blockIdx.x;
  const int b   = bid & 31;        // batch-b blocks share bid%8 -> same XCD L2
  const int r0  = (bid >> 5) << 6; // 16 row-blocks of 64

  const float* Ab = Ag + ((size_t)b * NN + r0) * NN;
  const unsigned short* hTb = hTg + (size_t)b * MM * NN;

  // ---- A direct-fragment pointers: row wr*32+{0,16}+l15, k = kk*32+lg*8 ----
  const float* ap0 = Ab + (size_t)((wr << 5) + l15) * NN + (lg << 3);
  const float* ap1 = ap0 + (size_t)16 * NN;

  // ---- H staging (r7-verified): [256 cols][128B], pre-swizzled source ----
  const unsigned short* baseH[4];
#pragma unroll
  for (int i = 0; i < 4; ++i) {
    int c = i * 512 + tid;           // 16B chunk id: [256 cols][8 chunks]
    int col = c >> 3, cic = c & 7;
    baseH[i] = hTb + (size_t)col * NN + ((cic ^ (col & 7)) << 3);
  }
  const int dstW = wid << 10;        // wave-uniform base (64 lanes x 16B)

#define STAGE_H(K0, HB)                                                      \
  do {                                                                       \
    _Pragma("unroll")                                                        \
    for (int i = 0; i < 4; ++i)                                              \
      gl_lds16(baseH[i] + (K0), smem + (HB) + dstW + i * 8192);              \
  } while (0)

  // pinned A prefetch regs: m{0,1} x kk{0,1} x half{lo,hi}
  float4 a00l, a00h, a01l, a01h, a10l, a10h, a11l, a11h;
#define ISSUE_A(K0)                                                          \
  do {                                                                       \
    a00l = gload_f4(ap0 + (K0));       a00h = gload_f4(ap0 + (K0) + 4);      \
    a01l = gload_f4(ap0 + (K0) + 32);  a01h = gload_f4(ap0 + (K0) + 36);     \
    a10l = gload_f4(ap1 + (K0));       a10h = gload_f4(ap1 + (K0) + 4);      \
    a11l = gload_f4(ap1 + (K0) + 32);  a11h = gload_f4(ap1 + (K0) + 36);     \
  } while (0)

  float pm0 = -1e30f, pm1 = -1e30f;
  bf16x8 af00, af01, af10, af11;
#define MAX8(L, H) fmaxf(fmaxf(fmaxf((L).x, (L).y), fmaxf((L).z, (L).w)),    \
                         fmaxf(fmaxf((H).x, (H).y), fmaxf((H).z, (H).w)))
#define CVT1(DST, L, H)                                                      \
  do {                                                                       \
    uint4 q = make_uint4(cvtpk((L).x, (L).y), cvtpk((L).z, (L).w),           \
                         cvtpk((H).x, (H).y), cvtpk((H).z, (H).w));          \
    DST = *reinterpret_cast<bf16x8*>(&q);                                    \
  } while (0)
#define CVT_A()                                                              \
  do {                                                                       \
    pm0 = fmaxf(pm0, fmaxf(MAX8(a00l, a00h), MAX8(a01l, a01h)));             \
    pm1 = fmaxf(pm1, fmaxf(MAX8(a10l, a10h), MAX8(a11l, a11h)));             \
    CVT1(af00, a00l, a00h); CVT1(af01, a01l, a01h);                          \
    CVT1(af10, a10l, a10h); CVT1(af11, a11l, a11h);                          \
  } while (0)

  f32x4 acc[2][4];
#pragma unroll
  for (int m = 0; m < 2; ++m)
#pragma unroll
    for (int n = 0; n < 4; ++n) acc[m][n] = f32x4{0.f, 0.f, 0.f, 0.f};

#define CONSUME(HB)                                                          \
  do {                                                                       \
    _Pragma("unroll")                                                        \
    for (int kk = 0; kk < 2; ++kk) {                                         \
      const int kb = (kk * 32 + (lg << 3)) * 2;                              \
      bf16x8 bh[4];                                                          \
      _Pragma("unroll")                                                      \
      for (int n = 0; n < 4; ++n) {                                          \
        int col = (wc << 6) + (n << 4) + l15;                                \
        bh[n] = *reinterpret_cast<const bf16x8*>(                            \
            smem + (HB) + col * 128 + (kb ^ ((col & 7) << 4)));              \
      }                                                                      \
      bf16x8 fa0 = kk ? af01 : af00;                                         \
      bf16x8 fa1 = kk ? af11 : af10;                                         \
      _Pragma("unroll")                                                      \
      for (int n = 0; n < 4; ++n) {                                          \
        acc[0][n] = __builtin_amdgcn_mfma_f32_16x16x32_bf16(fa0, bh[n],      \
                                                            acc[0][n], 0, 0, 0); \
        acc[1][n] = __builtin_amdgcn_mfma_f32_16x16x32_bf16(fa1, bh[n],      \
                                                            acc[1][n], 0, 0, 0); \
      }                                                                      \
    }                                                                        \
  } while (0)

  // ---- prologue: stage step 0 fully ----
  STAGE_H(0, HB_(0));
  ISSUE_A(0);
  VMW(0);
  __builtin_amdgcn_s_barrier();

  // ---- phase 1: 16 K-steps of 64, one barrier per step ----
#pragma unroll
  for (int t = 0; t < 16; ++t) {
    VMW(0);                                // A(t) regs landed (r13 fix)
    CVT_A();                               // A(t) -> bf16 frags (+rowmax)
    if (t < 15) {
      STAGE_H((t + 1) * 64, (t & 1) ? HB_(0) : HB_(1));  // H first (4 gl_lds)
      ISSUE_A((t + 1) * 64);                             // A second (8 loads)
    }
    CONSUME((t & 1) ? HB_(1) : HB_(0));
    if (t < 15) {
      VMW(8);                              // H(t+1) in LDS; A(t+1) still flying
      PIPE_BARRIER();
    }
  }

  // ---- rowmax finalize: reduce over lg; wc==0 writes ----
  {
    float v0 = pm0, v1 = pm1;
    v0 = fmaxf(v0, __shfl_xor(v0, 16));
    v0 = fmaxf(v0, __shfl_xor(v0, 32));
    v1 = fmaxf(v1, __shfl_xor(v1, 16));
    v1 = fmaxf(v1, __shfl_xor(v1, 32));
    if (wc == 0 && lg == 0) {
      smax[(wr << 5) + l15]      = v0;
      smax[(wr << 5) + 16 + l15] = v1;
    }
  }
  __syncthreads();   // phase-1 LDS fully retired before aliasing

  // ---- write k tile (/3, bf16) -> Kld [64][512B] XOR ----
  {
    const float inv3 = 1.0f / 3.0f;
#pragma unroll
    for (int m = 0; m < 2; ++m)
#pragma unroll
      for (int n = 0; n < 4; ++n) {
        int col = (wc << 6) + (n << 4) + l15;
#pragma unroll
        for (int j = 0; j < 4; ++j) {
          int row = (wr << 5) + (m << 4) + (lg << 2) + j;
          *reinterpret_cast<unsigned short*>(smem + KLD + row * 512 +
                                             ((col * 2) ^ ((row & 7) << 4))) =
              f2bf(acc[m][n][j] * inv3);
        }
      }
  }
  __syncthreads();

  // ---- GEMM1: y[64][128] = k @ W1 (W1T fragments straight from L2) ----
  f32x4 acc1[2][2];
#pragma unroll
  for (int m = 0; m < 2; ++m)
#pragma unroll
    for (int n = 0; n < 2; ++n) acc1[m][n] = f32x4{0.f, 0.f, 0.f, 0.f};
  const int wcol1 = wc << 5;  // 0,32,64,96
#pragma unroll
  for (int kq = 0; kq < 8; ++kq) {
    bf16x8 af[2], bw[2];
#pragma unroll
    for (int m = 0; m < 2; ++m) {
      int row = (wr << 5) + (m << 4) + l15;
      af[m] = *reinterpret_cast<const bf16x8*>(smem + KLD + row * 512 +
              (((kq * 32 + (lg << 3)) * 2) ^ ((row & 7) << 4)));
    }
#pragma unroll
    for (int n = 0; n < 2; ++n) {
      int col = wcol1 + (n << 4) + l15;
      bw[n] = *reinterpret_cast<const bf16x8*>(W1Tg + (size_t)col * 256 +
                                               kq * 32 + (lg << 3));
    }
#pragma unroll
    for (int m = 0; m < 2; ++m)
#pragma unroll
      for (int n = 0; n < 2; ++n)
        acc1[m][n] = __builtin_amdgcn_mfma_f32_16x16x32_bf16(af[m], bw[n], acc1[m][n], 0, 0, 0);
  }
  __syncthreads();  // Kld fully read

  // ---- c = relu(y+b1) -> Cld [64][256B] XOR (disjoint from Kld) ----
  {
#pragma unroll
    for (int n = 0; n < 2; ++n) {
      int col = wcol1 + (n << 4) + l15;
      float bias = b1g[col];
#pragma unroll
      for (int m = 0; m < 2; ++m)
#pragma unroll
        for (int j = 0; j < 4; ++j) {
          int row = (wr << 5) + (m << 4) + (lg << 2) + j;
          float v = fmaxf(acc1[m][n][j] + bias, 0.f);
          *reinterpret_cast<unsigned short*>(smem + CLD + row * 256 +
                                             ((col * 2) ^ ((row & 7) << 4))) = f2bf(v);
        }
    }
  }
  __syncthreads();

  // ---- GEMM2: out2[64][256] = c @ W2 (W2T fragments from L2) ----
  f32x4 acc2[2][4];
#pragma unroll
  for (int m = 0; m < 2; ++m)
#pragma unroll
    for (int n = 0; n < 4; ++n) acc2[m][n] = f32x4{0.f, 0.f, 0.f, 0.f};
#pragma unroll
  for (int kq = 0; kq < 4; ++kq) {
    bf16x8 af[2], bw[4];
#pragma unroll
    for (int m = 0; m < 2; ++m) {
      int row = (wr << 5) + (m << 4) + l15;
      af[m] = *reinterpret_cast<const bf16x8*>(smem + CLD + row * 256 +
              (((kq * 32 + (lg << 3)) * 2) ^ ((row & 7) << 4)));
    }
#pragma unroll
    for (int n = 0; n < 4; ++n) {
      int col = (wc << 6) + (n << 4) + l15;
      bw[n] = *reinterpret_cast<const bf16x8*>(W2Tg + (size_t)col * 128 +
                                               kq * 32 + (lg << 3));
    }
#pragma unroll
    for (int m = 0; m < 2; ++m)
#pragma unroll
      for (int n = 0; n < 4; ++n)
        acc2[m][n] = __builtin_amdgcn_mfma_f32_16x16x32_bf16(af[m], bw[n], acc2[m][n], 0, 0, 0);
  }

  // ---- epilogue: out = (out2+b2)*mask + h*(1-mask) ----
  {
#pragma unroll
    for (int n = 0; n < 4; ++n) {
      int col = (wc << 6) + (n << 4) + l15;
      float b2v = b2g[col];
#pragma unroll
      for (int m = 0; m < 2; ++m)
#pragma unroll
        for (int j = 0; j < 4; ++j) {
          int row = (wr << 5) + (m << 4) + (lg << 2) + j;
          float kv = acc2[m][n][j] + b2v;
          float mask = smax[row];
          size_t gidx = ((size_t)b * NN + r0 + row) * MM + col;
          float hv = hg[gidx];
          outg[gidx] = kv * mask + hv * (1.f - mask);
        }
    }
  }
#undef CONSUME
#undef CVT_A
#undef CVT1
#undef MAX8
#undef ISSUE_A
#undef STAGE_H
}

extern "C" void kernel_launch(void* const* d_in, const int* in_sizes, int n_in,
                              void* d_out, int out_size, void* d_ws, size_t ws_size,
                              hipStream_t stream) {
  (void)in_sizes; (void)n_in; (void)out_size; (void)ws_size;
  const float* A  = (const float*)d_in[0];
  const float* h  = (const float*)d_in[1];
  const float* W1 = (const float*)d_in[2];
  const float* b1 = (const float*)d_in[3];
  const float* W2 = (const float*)d_in[4];
  const float* b2 = (const float*)d_in[5];
  float* out = (float*)d_out;

  unsigned short* hT  = (unsigned short*)d_ws;
  unsigned short* W1T = (unsigned short*)((char*)d_ws + (size_t)BB * MM * NN * 2);
  unsigned short* W2T = W1T + MM * HH;

  k_prep<<<BB * 64 + 256, 256, 0, stream>>>(h, hT, W1, W2, W1T, W2T);
  k_fused<<<BB * 16, 512, 0, stream>>>(A, h, hT, W1T, W2T, b1, b2, out);
}

// Round 15
// 63.193 us; speedup vs baseline: 2.3205x; 1.6479x over previous
//
#include <hip/hip_runtime.h>

typedef __attribute__((ext_vector_type(8))) short bf16x8;
typedef __attribute__((ext_vector_type(4))) float f32x4;
typedef __attribute__((ext_vector_type(8))) unsigned short u16x8;

#define BB 32
#define NN 1024
#define MM 256
#define HH 128

__device__ __forceinline__ unsigned short f2bf(float f) {
  union { float f; unsigned int u; } c; c.f = f;
  unsigned int u = c.u + 0x7fffu + ((c.u >> 16) & 1u);  // RNE
  return (unsigned short)(u >> 16);
}
__device__ __forceinline__ unsigned int cvtpk(float lo, float hi) {
  unsigned int r;
  asm("v_cvt_pk_bf16_f32 %0, %1, %2" : "=v"(r) : "v"(lo), "v"(hi));
  return r;
}
__device__ __forceinline__ float4 gload_f4(const float* p) {
  float4 r;
  asm volatile("global_load_dwordx4 %0, %1, off" : "=v"(r) : "v"(p));
  return r;
}
typedef __attribute__((address_space(3))) unsigned int as3_u32;
typedef const __attribute__((address_space(1))) unsigned int as1_u32;
__device__ __forceinline__ void gl_lds16(const void* g, void* l) {
  __builtin_amdgcn_global_load_lds((as1_u32*)g, (as3_u32*)l, 16, 0, 0);
}

// ---------- combined pre-pass: hT (bf16 [B][M][N]) + W1T/W2T ----------
__global__ __launch_bounds__(256)
void k_prep(const float* __restrict__ hg, unsigned short* __restrict__ hTg,
            const float* __restrict__ W1, const float* __restrict__ W2,
            unsigned short* __restrict__ W1T, unsigned short* __restrict__ W2T) {
  int bid = blockIdx.x;
  if (bid < BB * 64) {
    __shared__ unsigned short tile[64][65];
    int b = bid >> 6;
    int t = bid & 63;
    int k0 = (t >> 2) << 6;
    int m0 = (t & 3) << 6;
    int tt = threadIdx.x;
    {
      int r = tt >> 2;
      int cg = (tt & 3) << 4;
      const float* src = hg + (((size_t)b * NN + k0 + r) * MM + m0 + cg);
#pragma unroll
      for (int i = 0; i < 4; ++i) {
        float4 v = reinterpret_cast<const float4*>(src)[i];
        tile[r][cg + i * 4 + 0] = f2bf(v.x);
        tile[r][cg + i * 4 + 1] = f2bf(v.y);
        tile[r][cg + i * 4 + 2] = f2bf(v.z);
        tile[r][cg + i * 4 + 3] = f2bf(v.w);
      }
    }
    __syncthreads();
    {
      int mr = tt >> 2;
      int kc = (tt & 3) << 4;
      alignas(16) unsigned short tmp[16];
#pragma unroll
      for (int i = 0; i < 16; ++i) tmp[i] = tile[kc + i][mr];
      unsigned short* dst = hTg + (((size_t)b * MM + m0 + mr) * NN + k0 + kc);
      *reinterpret_cast<u16x8*>(dst)     = *reinterpret_cast<u16x8*>(tmp);
      *reinterpret_cast<u16x8*>(dst + 8) = *reinterpret_cast<u16x8*>(tmp + 8);
    }
  } else {
    int idx = (bid - BB * 64) * 256 + threadIdx.x;
    if (idx < MM * HH) {
      int hc = idx >> 8;
      int m  = idx & 255;
      W1T[idx] = f2bf(W1[m * HH + hc]);
    } else {
      int j = idx - MM * HH;
      int m  = j >> 7;
      int hd = j & 127;
      W2T[j] = f2bf(W2[hd * MM + m]);
    }
  }
}

// ---------------- fused main (r7 skeleton; A-staging lane map remapped) ----
// 256 blocks x 512 threads (8 waves 2x4). Block tile 128 rows x 256 cols.
// CHANGE vs r7: A staging chunk c = i*512+tid -> row = i*32+(tid>>4),
// kchunk = tid&15: every wave load instruction covers 4 rows x 256 B fully
// CONTIGUOUS runs (was 16-B pieces at 64-B stride). Tests the hypothesis
// that 4KB-strided fragmented requests are what caps the A stream.
// Everything else (H gl_lds path, consume, phases 2/3, epilogue) = r7.
#define AB0 0
#define AB1 16384
#define HB0 32768
#define HB1 65536
#define KLD 0
#define CLD 65536

#define PIPE_BARRIER() do { \
  asm volatile("s_waitcnt lgkmcnt(0)" ::: "memory"); \
  __builtin_amdgcn_s_barrier(); \
  asm volatile("" ::: "memory"); } while (0)

#define VMWAIT0() do { \
  asm volatile("s_waitcnt vmcnt(0)" ::: "memory"); \
  __builtin_amdgcn_sched_barrier(0); } while (0)

__global__ __launch_bounds__(512, 1)
void k_fused(const float* __restrict__ Ag, const float* __restrict__ hg,
             const unsigned short* __restrict__ hTg,
             const unsigned short* __restrict__ W1Tg,
             const unsigned short* __restrict__ W2Tg,
             const float* __restrict__ b1g, const float* __restrict__ b2g,
             float* __restrict__ outg) {
  __shared__ __align__(16) char smem[98304];
  __shared__ float smax[128];

  const int tid  = threadIdx.x;
  const int lane = tid & 63;
  const int wid  = tid >> 6;       // 0..7
  const int wr   = wid >> 2;       // 0..1 (row half)
  const int wc   = wid & 3;        // 0..3 (col quarter)
  const int l15  = lane & 15;
  const int lg   = lane >> 4;      // 0..3

  const int bid = blockIdx.x;
  const int b   = bid & 31;        // same-batch blocks share bid%8 -> same XCD
  const int r0  = (bid >> 5) << 7; // 8 row-blocks of 128

  const float* Ab = Ag + ((size_t)b * NN + r0) * NN;
  const unsigned short* hTb = hTg + (size_t)b * MM * NN;

  // ---- A staging (NEW map): thread t, slice i -> row i*32+(t>>4), 16B
  // chunk t&15. Wave instruction = 4 rows x 256 B contiguous runs. ----
  const int agrp = tid >> 4;          // 0..31 (row within 32-row slice)
  const int akc  = tid & 15;          // 16B chunk within the 256B k-slice
  const float* apA0 = Ab + (size_t)(agrp)      * NN + (akc << 2);
  const float* apA1 = Ab + (size_t)(32 + agrp) * NN + (akc << 2);
  const float* apA2 = Ab + (size_t)(64 + agrp) * NN + (akc << 2);
  const float* apA3 = Ab + (size_t)(96 + agrp) * NN + (akc << 2);
  const int asw = (agrp & 7) << 4;    // row&7 == agrp&7 for all 4 slices

  // ---- H staging sources (r7-verified): pre-swizzled global, linear LDS ----
  const unsigned short* baseH[4];
#pragma unroll
  for (int i = 0; i < 4; ++i) {
    int c = i * 512 + tid;            // 16B chunk id: [256 cols][8 chunks]
    int col = c >> 3, cic = c & 7;
    baseH[i] = hTb + (size_t)col * NN + ((cic ^ (col & 7)) << 3);
  }
  const int ldsW = wid << 10;         // wave-uniform base (64 lanes x 16B)

#define STAGE_H(K0, HB)                                                     \
  do {                                                                      \
    _Pragma("unroll")                                                       \
    for (int i = 0; i < 4; ++i)                                             \
      gl_lds16(baseH[i] + (K0), smem + (HB) + ldsW + i * 8192);             \
  } while (0)

  float4 rA0, rA1, rA2, rA3;
#define ISSUE_A(K0)                                                         \
  do {                                                                      \
    rA0 = gload_f4(apA0 + (K0));                                            \
    rA1 = gload_f4(apA1 + (K0));                                            \
    rA2 = gload_f4(apA2 + (K0));                                            \
    rA3 = gload_f4(apA3 + (K0));                                            \
  } while (0)

  float pm0 = -1e30f, pm1 = -1e30f, pm2 = -1e30f, pm3 = -1e30f;
#define CVTWR(AB)                                                           \
  do {                                                                      \
    pm0 = fmaxf(pm0, fmaxf(fmaxf(rA0.x, rA0.y), fmaxf(rA0.z, rA0.w)));      \
    pm1 = fmaxf(pm1, fmaxf(fmaxf(rA1.x, rA1.y), fmaxf(rA1.z, rA1.w)));      \
    pm2 = fmaxf(pm2, fmaxf(fmaxf(rA2.x, rA2.y), fmaxf(rA2.z, rA2.w)));      \
    pm3 = fmaxf(pm3, fmaxf(fmaxf(rA3.x, rA3.y), fmaxf(rA3.z, rA3.w)));      \
    uint2 q0 = make_uint2(cvtpk(rA0.x, rA0.y), cvtpk(rA0.z, rA0.w));        \
    uint2 q1 = make_uint2(cvtpk(rA1.x, rA1.y), cvtpk(rA1.z, rA1.w));        \
    uint2 q2 = make_uint2(cvtpk(rA2.x, rA2.y), cvtpk(rA2.z, rA2.w));        \
    uint2 q3 = make_uint2(cvtpk(rA3.x, rA3.y), cvtpk(rA3.z, rA3.w));        \
    *reinterpret_cast<uint2*>(smem + (AB) + (agrp)      * 128 +             \
                              (((akc << 3)) ^ asw)) = q0;                   \
    *reinterpret_cast<uint2*>(smem + (AB) + (32 + agrp) * 128 +             \
                              (((akc << 3)) ^ asw)) = q1;                   \
    *reinterpret_cast<uint2*>(smem + (AB) + (64 + agrp) * 128 +             \
                              (((akc << 3)) ^ asw)) = q2;                   \
    *reinterpret_cast<uint2*>(smem + (AB) + (96 + agrp) * 128 +             \
                              (((akc << 3)) ^ asw)) = q3;                   \
  } while (0)

  f32x4 acc[4][4];
#pragma unroll
  for (int m = 0; m < 4; ++m)
#pragma unroll
    for (int n = 0; n < 4; ++n) acc[m][n] = f32x4{0.f, 0.f, 0.f, 0.f};

#define CONSUME(AB, HB)                                                     \
  do {                                                                      \
    _Pragma("unroll")                                                       \
    for (int kk = 0; kk < 2; ++kk) {                                        \
      const int kb = (kk * 32 + (lg << 3)) * 2;                             \
      bf16x8 af[4], bh[4];                                                  \
      _Pragma("unroll")                                                     \
      for (int m = 0; m < 4; ++m) {                                         \
        int row = (wr << 6) + (m << 4) + l15;                               \
        af[m] = *reinterpret_cast<const bf16x8*>(                           \
            smem + (AB) + row * 128 + (kb ^ ((row & 7) << 4)));             \
      }                                                                     \
      _Pragma("unroll")                                                     \
      for (int n = 0; n < 4; ++n) {                                         \
        int col = (wc << 6) + (n << 4) + l15;                               \
        bh[n] = *reinterpret_cast<const bf16x8*>(                           \
            smem + (HB) + col * 128 + (kb ^ ((col & 7) << 4)));             \
      }                                                                     \
      _Pragma("unroll")                                                     \
      for (int m = 0; m < 4; ++m)                                           \
        _Pragma("unroll")                                                   \
        for (int n = 0; n < 4; ++n)                                         \
          acc[m][n] = __builtin_amdgcn_mfma_f32_16x16x32_bf16(af[m], bh[n], \
                                                              acc[m][n], 0, 0, 0); \
    }                                                                       \
  } while (0)

  // ---- prologue: step 0 staged, barrier ----
  ISSUE_A(0);
  STAGE_H(0, HB0);
  VMWAIT0();
  CVTWR(AB0);
  PIPE_BARRIER();

  // ---- phase 1: 16 K-steps of 64 ----
#pragma unroll
  for (int t = 0; t < 16; ++t) {
    if (t < 15) {
      ISSUE_A((t + 1) * 64);
      STAGE_H((t + 1) * 64, (t & 1) ? HB0 : HB1);
    }
    if (t & 1) CONSUME(AB1, HB1);
    else       CONSUME(AB0, HB0);
    if (t < 15) {
      VMWAIT0();
      if (t & 1) CVTWR(AB0);
      else       CVTWR(AB1);
      PIPE_BARRIER();
    }
  }

  // ---- rowmax finalize: 16 lanes per row (bits 0-3), 4 rows per thread ----
  {
    float v0 = pm0, v1 = pm1, v2 = pm2, v3 = pm3;
#pragma unroll
    for (int s = 1; s < 16; s <<= 1) {
      v0 = fmaxf(v0, __shfl_xor(v0, s));
      v1 = fmaxf(v1, __shfl_xor(v1, s));
      v2 = fmaxf(v2, __shfl_xor(v2, s));
      v3 = fmaxf(v3, __shfl_xor(v3, s));
    }
    if ((tid & 15) == 0) {
      smax[agrp]      = v0;
      smax[32 + agrp] = v1;
      smax[64 + agrp] = v2;
      smax[96 + agrp] = v3;
    }
  }
  __syncthreads();   // phase-1 LDS fully retired before aliasing

  // ---- write k tile (/3, bf16) -> Kld [128][512B] XOR ----
  {
    const float inv3 = 1.0f / 3.0f;
#pragma unroll
    for (int m = 0; m < 4; ++m)
#pragma unroll
      for (int n = 0; n < 4; ++n) {
        int col = (wc << 6) + (n << 4) + l15;
#pragma unroll
        for (int j = 0; j < 4; ++j) {
          int row = (wr << 6) + (m << 4) + (lg << 2) + j;
          *reinterpret_cast<unsigned short*>(smem + KLD + row * 512 +
                                             ((col * 2) ^ ((row & 7) << 4))) =
              f2bf(acc[m][n][j] * inv3);
        }
      }
  }
  __syncthreads();

  // ---- GEMM1: y[128][128] = k @ W1 (W1T fragments straight from L2) ----
  f32x4 acc1[4][2];
#pragma unroll
  for (int m = 0; m < 4; ++m)
#pragma unroll
    for (int n = 0; n < 2; ++n) acc1[m][n] = f32x4{0.f, 0.f, 0.f, 0.f};
  const int wcol1 = wc << 5;  // 0,32,64,96
#pragma unroll
  for (int kq = 0; kq < 8; ++kq) {
    bf16x8 af[4], bw[2];
#pragma unroll
    for (int m = 0; m < 4; ++m) {
      int row = (wr << 6) + (m << 4) + l15;
      af[m] = *reinterpret_cast<const bf16x8*>(smem + KLD + row * 512 +
              (((kq * 32 + (lg << 3)) * 2) ^ ((row & 7) << 4)));
    }
#pragma unroll
    for (int n = 0; n < 2; ++n) {
      int col = wcol1 + (n << 4) + l15;
      bw[n] = *reinterpret_cast<const bf16x8*>(W1Tg + (size_t)col * 256 +
                                               kq * 32 + (lg << 3));
    }
#pragma unroll
    for (int m = 0; m < 4; ++m)
#pragma unroll
      for (int n = 0; n < 2; ++n)
        acc1[m][n] = __builtin_amdgcn_mfma_f32_16x16x32_bf16(af[m], bw[n], acc1[m][n], 0, 0, 0);
  }

  // ---- c = relu(y+b1) -> Cld [128][256B] XOR (disjoint from Kld) ----
  {
#pragma unroll
    for (int n = 0; n < 2; ++n) {
      int col = wcol1 + (n << 4) + l15;
      float bias = b1g[col];
#pragma unroll
      for (int m = 0; m < 4; ++m)
#pragma unroll
        for (int j = 0; j < 4; ++j) {
          int row = (wr << 6) + (m << 4) + (lg << 2) + j;
          float v = fmaxf(acc1[m][n][j] + bias, 0.f);
          *reinterpret_cast<unsigned short*>(smem + CLD + row * 256 +
                                             ((col * 2) ^ ((row & 7) << 4))) = f2bf(v);
        }
    }
  }
  __syncthreads();

  // ---- GEMM2: out2[128][256] = c @ W2 (W2T fragments from L2) ----
  f32x4 acc2[4][4];
#pragma unroll
  for (int m = 0; m < 4; ++m)
#pragma unroll
    for (int n = 0; n < 4; ++n) acc2[m][n] = f32x4{0.f, 0.f, 0.f, 0.f};
#pragma unroll
  for (int kq = 0; kq < 4; ++kq) {
    bf16x8 af[4], bw[4];
#pragma unroll
    for (int m = 0; m < 4; ++m) {
      int row = (wr << 6) + (m << 4) + l15;
      af[m] = *reinterpret_cast<const bf16x8*>(smem + CLD + row * 256 +
              (((kq * 32 + (lg << 3)) * 2) ^ ((row & 7) << 4)));
    }
#pragma unroll
    for (int n = 0; n < 4; ++n) {
      int col = (wc << 6) + (n << 4) + l15;
      bw[n] = *reinterpret_cast<const bf16x8*>(W2Tg + (size_t)col * 128 +
                                               kq * 32 + (lg << 3));
    }
#pragma unroll
    for (int m = 0; m < 4; ++m)
#pragma unroll
      for (int n = 0; n < 4; ++n)
        acc2[m][n] = __builtin_amdgcn_mfma_f32_16x16x32_bf16(af[m], bw[n], acc2[m][n], 0, 0, 0);
  }

  // ---- epilogue: out = (out2+b2)*mask + h*(1-mask) ----
  {
#pragma unroll
    for (int n = 0; n < 4; ++n) {
      int col = (wc << 6) + (n << 4) + l15;
      float b2v = b2g[col];
#pragma unroll
      for (int m = 0; m < 4; ++m)
#pragma unroll
        for (int j = 0; j < 4; ++j) {
          int row = (wr << 6) + (m << 4) + (lg << 2) + j;
          float kv = acc2[m][n][j] + b2v;
          float mask = smax[row];
          size_t gidx = ((size_t)b * NN + r0 + row) * MM + col;
          float hv = hg[gidx];
          outg[gidx] = kv * mask + hv * (1.f - mask);
        }
    }
  }
#undef CONSUME
#undef CVTWR
#undef ISSUE_A
#undef STAGE_H
}

extern "C" void kernel_launch(void* const* d_in, const int* in_sizes, int n_in,
                              void* d_out, int out_size, void* d_ws, size_t ws_size,
                              hipStream_t stream) {
  (void)in_sizes; (void)n_in; (void)out_size; (void)ws_size;
  const float* A  = (const float*)d_in[0];
  const float* h  = (const float*)d_in[1];
  const float* W1 = (const float*)d_in[2];
  const float* b1 = (const float*)d_in[3];
  const float* W2 = (const float*)d_in[4];
  const float* b2 = (const float*)d_in[5];
  float* out = (float*)d_out;

  unsigned short* hT  = (unsigned short*)d_ws;
  unsigned short* W1T = (unsigned short*)((char*)d_ws + (size_t)BB * MM * NN * 2);
  unsigned short* W2T = W1T + MM * HH;

  k_prep<<<BB * 64 + 256, 256, 0, stream>>>(h, hT, W1, W2, W1T, W2T);
  k_fused<<<BB * 8, 512, 0, stream>>>(A, h, hT, W1T, W2T, b1, b2, out);
}

// Round 16
// 58.285 us; speedup vs baseline: 2.5159x; 1.0842x over previous
//
#include <hip/hip_runtime.h>

typedef __attribute__((ext_vector_type(8))) short bf16x8;
typedef __attribute__((ext_vector_type(4))) float f32x4;
typedef __attribute__((ext_vector_type(8))) unsigned short u16x8;

#define BB 32
#define NN 1024
#define MM 256
#define HH 128

__device__ __forceinline__ unsigned short f2bf(float f) {
  union { float f; unsigned int u; } c; c.f = f;
  unsigned int u = c.u + 0x7fffu + ((c.u >> 16) & 1u);  // RNE
  return (unsigned short)(u >> 16);
}
__device__ __forceinline__ unsigned int cvtpk(float lo, float hi) {
  unsigned int r;
  asm("v_cvt_pk_bf16_f32 %0, %1, %2" : "=v"(r) : "v"(lo), "v"(hi));
  return r;
}
__device__ __forceinline__ float4 gload_f4(const float* p) {
  float4 r;
  asm volatile("global_load_dwordx4 %0, %1, off" : "=v"(r) : "v"(p));
  return r;
}
typedef __attribute__((address_space(3))) unsigned int as3_u32;
typedef const __attribute__((address_space(1))) unsigned int as1_u32;
__device__ __forceinline__ void gl_lds16(const void* g, void* l) {
  __builtin_amdgcn_global_load_lds((as1_u32*)g, (as3_u32*)l, 16, 0, 0);
}

// ---------- combined pre-pass: hT (bf16 [B][M][N]) + W1T/W2T ----------
__global__ __launch_bounds__(256)
void k_prep(const float* __restrict__ hg, unsigned short* __restrict__ hTg,
            const float* __restrict__ W1, const float* __restrict__ W2,
            unsigned short* __restrict__ W1T, unsigned short* __restrict__ W2T) {
  int bid = blockIdx.x;
  if (bid < BB * 64) {
    __shared__ unsigned short tile[64][65];
    int b = bid >> 6;
    int t = bid & 63;
    int k0 = (t >> 2) << 6;
    int m0 = (t & 3) << 6;
    int tt = threadIdx.x;
    {
      int r = tt >> 2;
      int cg = (tt & 3) << 4;
      const float* src = hg + (((size_t)b * NN + k0 + r) * MM + m0 + cg);
#pragma unroll
      for (int i = 0; i < 4; ++i) {
        float4 v = reinterpret_cast<const float4*>(src)[i];
        tile[r][cg + i * 4 + 0] = f2bf(v.x);
        tile[r][cg + i * 4 + 1] = f2bf(v.y);
        tile[r][cg + i * 4 + 2] = f2bf(v.z);
        tile[r][cg + i * 4 + 3] = f2bf(v.w);
      }
    }
    __syncthreads();
    {
      int mr = tt >> 2;
      int kc = (tt & 3) << 4;
      alignas(16) unsigned short tmp[16];
#pragma unroll
      for (int i = 0; i < 16; ++i) tmp[i] = tile[kc + i][mr];
      unsigned short* dst = hTg + (((size_t)b * MM + m0 + mr) * NN + k0 + kc);
      *reinterpret_cast<u16x8*>(dst)     = *reinterpret_cast<u16x8*>(tmp);
      *reinterpret_cast<u16x8*>(dst + 8) = *reinterpret_cast<u16x8*>(tmp + 8);
    }
  } else {
    int idx = (bid - BB * 64) * 256 + threadIdx.x;
    if (idx < MM * HH) {
      int hc = idx >> 8;
      int m  = idx & 255;
      W1T[idx] = f2bf(W1[m * HH + hc]);
    } else {
      int j = idx - MM * HH;
      int m  = j >> 7;
      int hd = j & 127;
      W2T[j] = f2bf(W2[hd * MM + m]);
    }
  }
}

// ---------------- fused main ----------------
// 512 blocks x 512 threads (8 waves = 2 row-halves x 4 col-quarters).
// Block tile 64 rows x 256 cols; per-wave 32x64; BK=64, 16 K-steps.
// LDS ~74 KB -> TWO independent blocks/CU (16 waves, 2 barrier groups):
// one block's MFMA/epilogue covers the other's vmcnt/barrier drains.
// A: r15-verified contiguous staging (4 rows x 256B runs/wave-instr),
//    pinned asm loads, SINGLE LDS buffer (B1 = plain s_barrier between
//    consume and the rewrite). H: r15-verified gl_lds dbuf, pre-swz src.
// LDS map: H0 @0 (32K), H1 @32K (32K), A @64K (8K)  = 73728 B.
//          phase2: Kld [64][512B]=32K @0 (alias H0); Cld 16K @32K (alias H1).
#define HB0 0
#define HB1 32768
#define ABUF 65536
#define KLD 0
#define CLD 32768

#define PIPE_BARRIER() do { \
  asm volatile("s_waitcnt lgkmcnt(0)" ::: "memory"); \
  __builtin_amdgcn_s_barrier(); \
  asm volatile("" ::: "memory"); } while (0)

#define VMWAIT0() do { \
  asm volatile("s_waitcnt vmcnt(0)" ::: "memory"); \
  __builtin_amdgcn_sched_barrier(0); } while (0)

__global__ __launch_bounds__(512)
void k_fused(const float* __restrict__ Ag, const float* __restrict__ hg,
             const unsigned short* __restrict__ hTg,
             const unsigned short* __restrict__ W1Tg,
             const unsigned short* __restrict__ W2Tg,
             const float* __restrict__ b1g, const float* __restrict__ b2g,
             float* __restrict__ outg) {
  __shared__ __align__(16) char smem[73728];
  __shared__ float smax[64];

  const int tid  = threadIdx.x;
  const int lane = tid & 63;
  const int wid  = tid >> 6;       // 0..7
  const int wr   = wid >> 2;       // 0..1 (row half, 32 rows)
  const int wc   = wid & 3;        // 0..3 (col quarter, 64 cols)
  const int l15  = lane & 15;
  const int lg   = lane >> 4;      // 0..3

  const int bid = blockIdx.x;
  const int b   = bid & 31;        // same-batch blocks share bid%8 -> same XCD
  const int r0  = (bid >> 5) << 6; // 16 row-blocks of 64

  const float* Ab = Ag + ((size_t)b * NN + r0) * NN;
  const unsigned short* hTb = hTg + (size_t)b * MM * NN;

  // ---- A staging (contiguous map): c = i*512+tid -> row=c>>4, 16B chunk
  // c&15.  Wave-instr = 4 rows x 256 B contiguous runs. ----
  const int arow0 = tid >> 4;          // rows 0..31 (i=0); +32 for i=1
  const int akc   = tid & 15;          // 16B fp32 chunk (-> 8B bf16 slot)
  const float* apA0 = Ab + (size_t)arow0        * NN + (akc << 2);
  const float* apA1 = Ab + (size_t)(32 + arow0) * NN + (akc << 2);

  // ---- H staging (r15-verified): [256 cols][128B], pre-swizzled source ----
  const unsigned short* baseH[4];
#pragma unroll
  for (int i = 0; i < 4; ++i) {
    int c = i * 512 + tid;             // 16B chunk id: [256 cols][8 chunks]
    int col = c >> 3, cic = c & 7;
    baseH[i] = hTb + (size_t)col * NN + ((cic ^ (col & 7)) << 3);
  }
  const int ldsW = wid << 10;          // wave-uniform base (64 lanes x 16B)

#define STAGE_H(K0, HB)                                                     \
  do {                                                                      \
    _Pragma("unroll")                                                       \
    for (int i = 0; i < 4; ++i)                                             \
      gl_lds16(baseH[i] + (K0), smem + (HB) + ldsW + i * 8192);             \
  } while (0)

  float4 rA0, rA1;
#define ISSUE_A(K0)                                                         \
  do {                                                                      \
    rA0 = gload_f4(apA0 + (K0));                                            \
    rA1 = gload_f4(apA1 + (K0));                                            \
  } while (0)

  float pm0 = -1e30f, pm1 = -1e30f;
#define CVTWR()                                                             \
  do {                                                                      \
    pm0 = fmaxf(pm0, fmaxf(fmaxf(rA0.x, rA0.y), fmaxf(rA0.z, rA0.w)));      \
    pm1 = fmaxf(pm1, fmaxf(fmaxf(rA1.x, rA1.y), fmaxf(rA1.z, rA1.w)));      \
    uint2 q0 = make_uint2(cvtpk(rA0.x, rA0.y), cvtpk(rA0.z, rA0.w));        \
    uint2 q1 = make_uint2(cvtpk(rA1.x, rA1.y), cvtpk(rA1.z, rA1.w));        \
    *reinterpret_cast<uint2*>(smem + ABUF + (arow0)      * 128 +            \
                              ((akc << 3) ^ ((arow0 & 7) << 4))) = q0;      \
    *reinterpret_cast<uint2*>(smem + ABUF + (32 + arow0) * 128 +            \
                              ((akc << 3) ^ ((arow0 & 7) << 4))) = q1;      \
  } while (0)

  f32x4 acc[2][4];
#pragma unroll
  for (int m = 0; m < 2; ++m)
#pragma unroll
    for (int n = 0; n < 4; ++n) acc[m][n] = f32x4{0.f, 0.f, 0.f, 0.f};

#define CONSUME(HB)                                                         \
  do {                                                                      \
    _Pragma("unroll")                                                       \
    for (int kk = 0; kk < 2; ++kk) {                                        \
      const int kb = (kk * 32 + (lg << 3)) * 2;                             \
      bf16x8 af[2], bh[4];                                                  \
      _Pragma("unroll")                                                     \
      for (int m = 0; m < 2; ++m) {                                         \
        int row = (wr << 5) + (m << 4) + l15;                               \
        af[m] = *reinterpret_cast<const bf16x8*>(                           \
            smem + ABUF + row * 128 + (kb ^ ((row & 7) << 4)));             \
      }                                                                     \
      _Pragma("unroll")                                                     \
      for (int n = 0; n < 4; ++n) {                                         \
        int col = (wc << 6) + (n << 4) + l15;                               \
        bh[n] = *reinterpret_cast<const bf16x8*>(                           \
            smem + (HB) + col * 128 + (kb ^ ((col & 7) << 4)));             \
      }                                                                     \
      _Pragma("unroll")                                                     \
      for (int m = 0; m < 2; ++m)                                           \
        _Pragma("unroll")                                                   \
        for (int n = 0; n < 4; ++n)                                         \
          acc[m][n] = __builtin_amdgcn_mfma_f32_16x16x32_bf16(af[m], bh[n], \
                                                              acc[m][n], 0, 0, 0); \
    }                                                                       \
  } while (0)

  // ---- prologue: step 0 staged, barrier ----
  STAGE_H(0, HB0);
  ISSUE_A(0);
  VMWAIT0();
  CVTWR();
  PIPE_BARRIER();

  // ---- phase 1: 16 K-steps of 64 ----
#pragma unroll
  for (int t = 0; t < 16; ++t) {
    if (t < 15) {
      STAGE_H((t + 1) * 64, (t & 1) ? HB0 : HB1);  // H(t+1) -> other buf
      ISSUE_A((t + 1) * 64);                       // A(t+1) -> pinned regs
    }
    CONSUME((t & 1) ? HB1 : HB0);
    __builtin_amdgcn_s_barrier();                  // B1: A-buf readers done
    if (t < 15) {
      VMWAIT0();                                   // H(t+1) in LDS, A(t+1) regs
      CVTWR();                                     // rewrite single A-buf
      PIPE_BARRIER();                              // B2: A visible
    }
  }

  // ---- rowmax finalize: reduce over lane bits 0-3 (16 staging lanes/row) ----
  {
    float v0 = pm0, v1 = pm1;
#pragma unroll
    for (int s = 1; s < 16; s <<= 1) {
      v0 = fmaxf(v0, __shfl_xor(v0, s));
      v1 = fmaxf(v1, __shfl_xor(v1, s));
    }
    if ((tid & 15) == 0) {
      smax[arow0]      = v0;
      smax[32 + arow0] = v1;
    }
  }
  __syncthreads();   // phase-1 LDS fully retired before aliasing

  // ---- write k tile (/3, bf16) -> Kld [64][512B] XOR @0 (alias H0) ----
  {
    const float inv3 = 1.0f / 3.0f;
#pragma unroll
    for (int m = 0; m < 2; ++m)
#pragma unroll
      for (int n = 0; n < 4; ++n) {
        int col = (wc << 6) + (n << 4) + l15;
#pragma unroll
        for (int j = 0; j < 4; ++j) {
          int row = (wr << 5) + (m << 4) + (lg << 2) + j;
          *reinterpret_cast<unsigned short*>(smem + KLD + row * 512 +
                                             ((col * 2) ^ ((row & 7) << 4))) =
              f2bf(acc[m][n][j] * inv3);
        }
      }
  }
  __syncthreads();

  // ---- GEMM1: y[64][128] = k @ W1 (W1T fragments straight from L2) ----
  f32x4 acc1[2][2];
#pragma unroll
  for (int m = 0; m < 2; ++m)
#pragma unroll
    for (int n = 0; n < 2; ++n) acc1[m][n] = f32x4{0.f, 0.f, 0.f, 0.f};
  const int wcol1 = wc << 5;  // 0,32,64,96
#pragma unroll
  for (int kq = 0; kq < 8; ++kq) {
    bf16x8 af[2], bw[2];
#pragma unroll
    for (int m = 0; m < 2; ++m) {
      int row = (wr << 5) + (m << 4) + l15;
      af[m] = *reinterpret_cast<const bf16x8*>(smem + KLD + row * 512 +
              (((kq * 32 + (lg << 3)) * 2) ^ ((row & 7) << 4)));
    }
#pragma unroll
    for (int n = 0; n < 2; ++n) {
      int col = wcol1 + (n << 4) + l15;
      bw[n] = *reinterpret_cast<const bf16x8*>(W1Tg + (size_t)col * 256 +
                                               kq * 32 + (lg << 3));
    }
#pragma unroll
    for (int m = 0; m < 2; ++m)
#pragma unroll
      for (int n = 0; n < 2; ++n)
        acc1[m][n] = __builtin_amdgcn_mfma_f32_16x16x32_bf16(af[m], bw[n], acc1[m][n], 0, 0, 0);
  }
  __syncthreads();  // Kld fully read

  // ---- c = relu(y+b1) -> Cld [64][256B] XOR @32K (alias H1, disjoint) ----
  {
#pragma unroll
    for (int n = 0; n < 2; ++n) {
      int col = wcol1 + (n << 4) + l15;
      float bias = b1g[col];
#pragma unroll
      for (int m = 0; m < 2; ++m)
#pragma unroll
        for (int j = 0; j < 4; ++j) {
          int row = (wr << 5) + (m << 4) + (lg << 2) + j;
          float v = fmaxf(acc1[m][n][j] + bias, 0.f);
          *reinterpret_cast<unsigned short*>(smem + CLD + row * 256 +
                                             ((col * 2) ^ ((row & 7) << 4))) = f2bf(v);
        }
    }
  }
  __syncthreads();

  // ---- GEMM2: out2[64][256] = c @ W2 (W2T fragments from L2) ----
  f32x4 acc2[2][4];
#pragma unroll
  for (int m = 0; m < 2; ++m)
#pragma unroll
    for (int n = 0; n < 4; ++n) acc2[m][n] = f32x4{0.f, 0.f, 0.f, 0.f};
#pragma unroll
  for (int kq = 0; kq < 4; ++kq) {
    bf16x8 af[2], bw[4];
#pragma unroll
    for (int m = 0; m < 2; ++m) {
      int row = (wr << 5) + (m << 4) + l15;
      af[m] = *reinterpret_cast<const bf16x8*>(smem + CLD + row * 256 +
              (((kq * 32 + (lg << 3)) * 2) ^ ((row & 7) << 4)));
    }
#pragma unroll
    for (int n = 0; n < 4; ++n) {
      int col = (wc << 6) + (n << 4) + l15;
      bw[n] = *reinterpret_cast<const bf16x8*>(W2Tg + (size_t)col * 128 +
                                               kq * 32 + (lg << 3));
    }
#pragma unroll
    for (int m = 0; m < 2; ++m)
#pragma unroll
      for (int n = 0; n < 4; ++n)
        acc2[m][n] = __builtin_amdgcn_mfma_f32_16x16x32_bf16(af[m], bw[n], acc2[m][n], 0, 0, 0);
  }

  // ---- epilogue: out = (out2+b2)*mask + h*(1-mask) ----
  {
#pragma unroll
    for (int n = 0; n < 4; ++n) {
      int col = (wc << 6) + (n << 4) + l15;
      float b2v = b2g[col];
#pragma unroll
      for (int m = 0; m < 2; ++m)
#pragma unroll
        for (int j = 0; j < 4; ++j) {
          int row = (wr << 5) + (m << 4) + (lg << 2) + j;
          float kv = acc2[m][n][j] + b2v;
          float mask = smax[row];
          size_t gidx = ((size_t)b * NN + r0 + row) * MM + col;
          float hv = hg[gidx];
          outg[gidx] = kv * mask + hv * (1.f - mask);
        }
    }
  }
#undef CONSUME
#undef CVTWR
#undef ISSUE_A
#undef STAGE_H
}

extern "C" void kernel_launch(void* const* d_in, const int* in_sizes, int n_in,
                              void* d_out, int out_size, void* d_ws, size_t ws_size,
                              hipStream_t stream) {
  (void)in_sizes; (void)n_in; (void)out_size; (void)ws_size;
  const float* A  = (const float*)d_in[0];
  const float* h  = (const float*)d_in[1];
  const float* W1 = (const float*)d_in[2];
  const float* b1 = (const float*)d_in[3];
  const float* W2 = (const float*)d_in[4];
  const float* b2 = (const float*)d_in[5];
  float* out = (float*)d_out;

  unsigned short* hT  = (unsigned short*)d_ws;
  unsigned short* W1T = (unsigned short*)((char*)d_ws + (size_t)BB * MM * NN * 2);
  unsigned short* W2T = W1T + MM * HH;

  k_prep<<<BB * 64 + 256, 256, 0, stream>>>(h, hT, W1, W2, W1T, W2T);
  k_fused<<<BB * 16, 512, 0, stream>>>(A, h, hT, W1T, W2T, b1, b2, out);
}

// Round 17
// 58.011 us; speedup vs baseline: 2.5278x; 1.0047x over previous
//
#include <hip/hip_runtime.h>

typedef __attribute__((ext_vector_type(8))) short bf16x8;
typedef __attribute__((ext_vector_type(4))) float f32x4;
typedef __attribute__((ext_vector_type(8))) unsigned short u16x8;

#define BB 32
#define NN 1024
#define MM 256
#define HH 128

__device__ __forceinline__ unsigned short f2bf(float f) {
  union { float f; unsigned int u; } c; c.f = f;
  unsigned int u = c.u + 0x7fffu + ((c.u >> 16) & 1u);  // RNE
  return (unsigned short)(u >> 16);
}
__device__ __forceinline__ unsigned int cvtpk(float lo, float hi) {
  unsigned int r;
  asm("v_cvt_pk_bf16_f32 %0, %1, %2" : "=v"(r) : "v"(lo), "v"(hi));
  return r;
}
__device__ __forceinline__ float4 gload_f4(const float* p) {
  float4 r;
  asm volatile("global_load_dwordx4 %0, %1, off" : "=v"(r) : "v"(p));
  return r;
}
typedef __attribute__((address_space(3))) unsigned int as3_u32;
typedef const __attribute__((address_space(1))) unsigned int as1_u32;
__device__ __forceinline__ void gl_lds16(const void* g, void* l) {
  __builtin_amdgcn_global_load_lds((as1_u32*)g, (as3_u32*)l, 16, 0, 0);
}

// ---------- combined pre-pass: hT (bf16 [B][M][N]) + W1T/W2T ----------
__global__ __launch_bounds__(256)
void k_prep(const float* __restrict__ hg, unsigned short* __restrict__ hTg,
            const float* __restrict__ W1, const float* __restrict__ W2,
            unsigned short* __restrict__ W1T, unsigned short* __restrict__ W2T) {
  int bid = blockIdx.x;
  if (bid < BB * 64) {
    __shared__ unsigned short tile[64][65];
    int b = bid >> 6;
    int t = bid & 63;
    int k0 = (t >> 2) << 6;
    int m0 = (t & 3) << 6;
    int tt = threadIdx.x;
    {
      int r = tt >> 2;
      int cg = (tt & 3) << 4;
      const float* src = hg + (((size_t)b * NN + k0 + r) * MM + m0 + cg);
#pragma unroll
      for (int i = 0; i < 4; ++i) {
        float4 v = reinterpret_cast<const float4*>(src)[i];
        tile[r][cg + i * 4 + 0] = f2bf(v.x);
        tile[r][cg + i * 4 + 1] = f2bf(v.y);
        tile[r][cg + i * 4 + 2] = f2bf(v.z);
        tile[r][cg + i * 4 + 3] = f2bf(v.w);
      }
    }
    __syncthreads();
    {
      int mr = tt >> 2;
      int kc = (tt & 3) << 4;
      alignas(16) unsigned short tmp[16];
#pragma unroll
      for (int i = 0; i < 16; ++i) tmp[i] = tile[kc + i][mr];
      unsigned short* dst = hTg + (((size_t)b * MM + m0 + mr) * NN + k0 + kc);
      *reinterpret_cast<u16x8*>(dst)     = *reinterpret_cast<u16x8*>(tmp);
      *reinterpret_cast<u16x8*>(dst + 8) = *reinterpret_cast<u16x8*>(tmp + 8);
    }
  } else {
    int idx = (bid - BB * 64) * 256 + threadIdx.x;
    if (idx < MM * HH) {
      int hc = idx >> 8;
      int m  = idx & 255;
      W1T[idx] = f2bf(W1[m * HH + hc]);
    } else {
      int j = idx - MM * HH;
      int m  = j >> 7;
      int hd = j & 127;
      W2T[j] = f2bf(W2[hd * MM + m]);
    }
  }
}

// ---------------- fused main ----------------
// 512 blocks x 512 threads (8 waves = 2 row-halves x 4 col-quarters).
// Block tile 64 rows x 256 cols; per-wave 32x64; BK=64, 16 K-steps.
// r16 + A double-buffered in LDS -> ONE barrier per step (B1 deleted).
// Per step t: [issue A(t+1) regs FIRST, then H(t+1) gl_lds] -> CONSUME(t)
//   -> vmcnt(4) [A(t+1) landed; H(t+1) still flying] -> CVTWR into the
//   OTHER A-buf (its readers retired at the previous barrier) -> vmcnt(0)
//   [H(t+1) in LDS] -> lgkm-barrier.
// LDS map (81920 B = 80 KiB exactly -> 2 blocks/CU):
//   H0 @0 (32K), H1 @32K (32K), A0 @64K (8K), A1 @72K (8K)
//   phase2 alias: Kld [64][512B] @0, Cld [64][256B] @32K,
//   smax (float[64]) @64K (aliases A0, dead after phase 1).
#define HB0 0
#define HB1 32768
#define AB0 65536
#define AB1 73728
#define KLD 0
#define CLD 32768
#define SMAXOFF 65536

#define PIPE_BARRIER() do { \
  asm volatile("s_waitcnt lgkmcnt(0)" ::: "memory"); \
  __builtin_amdgcn_s_barrier(); \
  asm volatile("" ::: "memory"); } while (0)

#define VMW(N) do { asm volatile("s_waitcnt vmcnt(" #N ")" ::: "memory"); \
  __builtin_amdgcn_sched_barrier(0); } while (0)

__global__ __launch_bounds__(512)
void k_fused(const float* __restrict__ Ag, const float* __restrict__ hg,
             const unsigned short* __restrict__ hTg,
             const unsigned short* __restrict__ W1Tg,
             const unsigned short* __restrict__ W2Tg,
             const float* __restrict__ b1g, const float* __restrict__ b2g,
             float* __restrict__ outg) {
  __shared__ __align__(16) char smem[81920];
  float* smax = reinterpret_cast<float*>(smem + SMAXOFF);

  const int tid  = threadIdx.x;
  const int lane = tid & 63;
  const int wid  = tid >> 6;       // 0..7
  const int wr   = wid >> 2;       // 0..1 (row half, 32 rows)
  const int wc   = wid & 3;        // 0..3 (col quarter, 64 cols)
  const int l15  = lane & 15;
  const int lg   = lane >> 4;      // 0..3

  const int bid = blockIdx.x;
  const int b   = bid & 31;        // same-batch blocks share bid%8 -> same XCD
  const int r0  = (bid >> 5) << 6; // 16 row-blocks of 64

  const float* Ab = Ag + ((size_t)b * NN + r0) * NN;
  const unsigned short* hTb = hTg + (size_t)b * MM * NN;

  // ---- A staging (r15/r16-verified contiguous map): c = i*512+tid ->
  // row = i*32 + (tid>>4), 16B chunk tid&15; 4 rows x 256B runs/wave-instr ----
  const int arow0 = tid >> 4;          // rows 0..31 (i=0); +32 for i=1
  const int akc   = tid & 15;          // 16B fp32 chunk (-> 8B bf16 slot)
  const float* apA0 = Ab + (size_t)arow0        * NN + (akc << 2);
  const float* apA1 = Ab + (size_t)(32 + arow0) * NN + (akc << 2);

  // ---- H staging (r15/r16-verified): [256 cols][128B], pre-swizzled src ----
  const unsigned short* baseH[4];
#pragma unroll
  for (int i = 0; i < 4; ++i) {
    int c = i * 512 + tid;             // 16B chunk id: [256 cols][8 chunks]
    int col = c >> 3, cic = c & 7;
    baseH[i] = hTb + (size_t)col * NN + ((cic ^ (col & 7)) << 3);
  }
  const int ldsW = wid << 10;          // wave-uniform base (64 lanes x 16B)

#define STAGE_H(K0, HB)                                                     \
  do {                                                                      \
    _Pragma("unroll")                                                       \
    for (int i = 0; i < 4; ++i)                                             \
      gl_lds16(baseH[i] + (K0), smem + (HB) + ldsW + i * 8192);             \
  } while (0)

  float4 rA0, rA1;
#define ISSUE_A(K0)                                                         \
  do {                                                                      \
    rA0 = gload_f4(apA0 + (K0));                                            \
    rA1 = gload_f4(apA1 + (K0));                                            \
  } while (0)

  float pm0 = -1e30f, pm1 = -1e30f;
#define CVTWR(AB)                                                           \
  do {                                                                      \
    pm0 = fmaxf(pm0, fmaxf(fmaxf(rA0.x, rA0.y), fmaxf(rA0.z, rA0.w)));      \
    pm1 = fmaxf(pm1, fmaxf(fmaxf(rA1.x, rA1.y), fmaxf(rA1.z, rA1.w)));      \
    uint2 q0 = make_uint2(cvtpk(rA0.x, rA0.y), cvtpk(rA0.z, rA0.w));        \
    uint2 q1 = make_uint2(cvtpk(rA1.x, rA1.y), cvtpk(rA1.z, rA1.w));        \
    *reinterpret_cast<uint2*>(smem + (AB) + (arow0)      * 128 +            \
                              ((akc << 3) ^ ((arow0 & 7) << 4))) = q0;      \
    *reinterpret_cast<uint2*>(smem + (AB) + (32 + arow0) * 128 +            \
                              ((akc << 3) ^ ((arow0 & 7) << 4))) = q1;      \
  } while (0)

  f32x4 acc[2][4];
#pragma unroll
  for (int m = 0; m < 2; ++m)
#pragma unroll
    for (int n = 0; n < 4; ++n) acc[m][n] = f32x4{0.f, 0.f, 0.f, 0.f};

#define CONSUME(AB, HB)                                                     \
  do {                                                                      \
    _Pragma("unroll")                                                       \
    for (int kk = 0; kk < 2; ++kk) {                                        \
      const int kb = (kk * 32 + (lg << 3)) * 2;                             \
      bf16x8 af[2], bh[4];                                                  \
      _Pragma("unroll")                                                     \
      for (int m = 0; m < 2; ++m) {                                         \
        int row = (wr << 5) + (m << 4) + l15;                               \
        af[m] = *reinterpret_cast<const bf16x8*>(                           \
            smem + (AB) + row * 128 + (kb ^ ((row & 7) << 4)));             \
      }                                                                     \
      _Pragma("unroll")                                                     \
      for (int n = 0; n < 4; ++n) {                                         \
        int col = (wc << 6) + (n << 4) + l15;                               \
        bh[n] = *reinterpret_cast<const bf16x8*>(                           \
            smem + (HB) + col * 128 + (kb ^ ((col & 7) << 4)));             \
      }                                                                     \
      _Pragma("unroll")                                                     \
      for (int m = 0; m < 2; ++m)                                           \
        _Pragma("unroll")                                                   \
        for (int n = 0; n < 4; ++n)                                         \
          acc[m][n] = __builtin_amdgcn_mfma_f32_16x16x32_bf16(af[m], bh[n], \
                                                              acc[m][n], 0, 0, 0); \
    }                                                                       \
  } while (0)

  // ---- prologue: A(0) regs + H(0) LDS; cvt A(0) -> AB0 ----
  ISSUE_A(0);                    // 2 loads (oldest)
  STAGE_H(0, HB0);               // 4 gl_lds
  VMW(4);                        // A(0) regs landed; H(0) still flying
  CVTWR(AB0);
  VMW(0);                        // H(0) in LDS
  PIPE_BARRIER();

  // ---- phase 1: 16 K-steps of 64, ONE barrier per step ----
#pragma unroll
  for (int t = 0; t < 16; ++t) {
    if (t < 15) {
      ISSUE_A((t + 1) * 64);                       // A(t+1) regs (oldest)
      STAGE_H((t + 1) * 64, (t & 1) ? HB0 : HB1);  // H(t+1) -> other buf
    }
    CONSUME((t & 1) ? AB1 : AB0, (t & 1) ? HB1 : HB0);
    if (t < 15) {
      VMW(4);                                      // A(t+1) landed
      CVTWR((t & 1) ? AB0 : AB1);                  // -> other A-buf
      VMW(0);                                      // H(t+1) in LDS
      PIPE_BARRIER();
    }
  }

  // ---- rowmax finalize: reduce over lane bits 0-3 (16 staging lanes/row) ----
  {
    float v0 = pm0, v1 = pm1;
#pragma unroll
    for (int s = 1; s < 16; s <<= 1) {
      v0 = fmaxf(v0, __shfl_xor(v0, s));
      v1 = fmaxf(v1, __shfl_xor(v1, s));
    }
    if ((tid & 15) == 0) {
      smax[arow0]      = v0;      // aliases AB0 (dead after phase 1)
      smax[32 + arow0] = v1;
    }
  }
  __syncthreads();   // phase-1 LDS fully retired before aliasing

  // ---- write k tile (/3, bf16) -> Kld [64][512B] XOR @0 (alias H0) ----
  {
    const float inv3 = 1.0f / 3.0f;
#pragma unroll
    for (int m = 0; m < 2; ++m)
#pragma unroll
      for (int n = 0; n < 4; ++n) {
        int col = (wc << 6) + (n << 4) + l15;
#pragma unroll
        for (int j = 0; j < 4; ++j) {
          int row = (wr << 5) + (m << 4) + (lg << 2) + j;
          *reinterpret_cast<unsigned short*>(smem + KLD + row * 512 +
                                             ((col * 2) ^ ((row & 7) << 4))) =
              f2bf(acc[m][n][j] * inv3);
        }
      }
  }
  __syncthreads();

  // ---- GEMM1: y[64][128] = k @ W1 (W1T fragments straight from L2) ----
  f32x4 acc1[2][2];
#pragma unroll
  for (int m = 0; m < 2; ++m)
#pragma unroll
    for (int n = 0; n < 2; ++n) acc1[m][n] = f32x4{0.f, 0.f, 0.f, 0.f};
  const int wcol1 = wc << 5;  // 0,32,64,96
#pragma unroll
  for (int kq = 0; kq < 8; ++kq) {
    bf16x8 af[2], bw[2];
#pragma unroll
    for (int m = 0; m < 2; ++m) {
      int row = (wr << 5) + (m << 4) + l15;
      af[m] = *reinterpret_cast<const bf16x8*>(smem + KLD + row * 512 +
              (((kq * 32 + (lg << 3)) * 2) ^ ((row & 7) << 4)));
    }
#pragma unroll
    for (int n = 0; n < 2; ++n) {
      int col = wcol1 + (n << 4) + l15;
      bw[n] = *reinterpret_cast<const bf16x8*>(W1Tg + (size_t)col * 256 +
                                               kq * 32 + (lg << 3));
    }
#pragma unroll
    for (int m = 0; m < 2; ++m)
#pragma unroll
      for (int n = 0; n < 2; ++n)
        acc1[m][n] = __builtin_amdgcn_mfma_f32_16x16x32_bf16(af[m], bw[n], acc1[m][n], 0, 0, 0);
  }
  __syncthreads();  // Kld fully read

  // ---- c = relu(y+b1) -> Cld [64][256B] XOR @32K (alias H1, disjoint) ----
  {
#pragma unroll
    for (int n = 0; n < 2; ++n) {
      int col = wcol1 + (n << 4) + l15;
      float bias = b1g[col];
#pragma unroll
      for (int m = 0; m < 2; ++m)
#pragma unroll
        for (int j = 0; j < 4; ++j) {
          int row = (wr << 5) + (m << 4) + (lg << 2) + j;
          float v = fmaxf(acc1[m][n][j] + bias, 0.f);
          *reinterpret_cast<unsigned short*>(smem + CLD + row * 256 +
                                             ((col * 2) ^ ((row & 7) << 4))) = f2bf(v);
        }
    }
  }
  __syncthreads();

  // ---- GEMM2: out2[64][256] = c @ W2 (W2T fragments from L2) ----
  f32x4 acc2[2][4];
#pragma unroll
  for (int m = 0; m < 2; ++m)
#pragma unroll
    for (int n = 0; n < 4; ++n) acc2[m][n] = f32x4{0.f, 0.f, 0.f, 0.f};
#pragma unroll
  for (int kq = 0; kq < 4; ++kq) {
    bf16x8 af[2], bw[4];
#pragma unroll
    for (int m = 0; m < 2; ++m) {
      int row = (wr << 5) + (m << 4) + l15;
      af[m] = *reinterpret_cast<const bf16x8*>(smem + CLD + row * 256 +
              (((kq * 32 + (lg << 3)) * 2) ^ ((row & 7) << 4)));
    }
#pragma unroll
    for (int n = 0; n < 4; ++n) {
      int col = (wc << 6) + (n << 4) + l15;
      bw[n] = *reinterpret_cast<const bf16x8*>(W2Tg + (size_t)col * 128 +
                                               kq * 32 + (lg << 3));
    }
#pragma unroll
    for (int m = 0; m < 2; ++m)
#pragma unroll
      for (int n = 0; n < 4; ++n)
        acc2[m][n] = __builtin_amdgcn_mfma_f32_16x16x32_bf16(af[m], bw[n], acc2[m][n], 0, 0, 0);
  }

  // ---- epilogue: out = (out2+b2)*mask + h*(1-mask) ----
  {
#pragma unroll
    for (int n = 0; n < 4; ++n) {
      int col = (wc << 6) + (n << 4) + l15;
      float b2v = b2g[col];
#pragma unroll
      for (int m = 0; m < 2; ++m)
#pragma unroll
        for (int j = 0; j < 4; ++j) {
          int row = (wr << 5) + (m << 4) + (lg << 2) + j;
          float kv = acc2[m][n][j] + b2v;
          float mask = smax[row];
          size_t gidx = ((size_t)b * NN + r0 + row) * MM + col;
          float hv = hg[gidx];
          outg[gidx] = kv * mask + hv * (1.f - mask);
        }
    }
  }
#undef CONSUME
#undef CVTWR
#undef ISSUE_A
#undef STAGE_H
}

extern "C" void kernel_launch(void* const* d_in, const int* in_sizes, int n_in,
                              void* d_out, int out_size, void* d_ws, size_t ws_size,
                              hipStream_t stream) {
  (void)in_sizes; (void)n_in; (void)out_size; (void)ws_size;
  const float* A  = (const float*)d_in[0];
  const float* h  = (const float*)d_in[1];
  const float* W1 = (const float*)d_in[2];
  const float* b1 = (const float*)d_in[3];
  const float* W2 = (const float*)d_in[4];
  const float* b2 = (const float*)d_in[5];
  float* out = (float*)d_out;

  unsigned short* hT  = (unsigned short*)d_ws;
  unsigned short* W1T = (unsigned short*)((char*)d_ws + (size_t)BB * MM * NN * 2);
  unsigned short* W2T = W1T + MM * HH;

  k_prep<<<BB * 64 + 256, 256, 0, stream>>>(h, hT, W1, W2, W1T, W2T);
  k_fused<<<BB * 16, 512, 0, stream>>>(A, h, hT, W1T, W2T, b1, b2, out);
}

// Round 18
// 57.987 us; speedup vs baseline: 2.5288x; 1.0004x over previous
//
#include <hip/hip_runtime.h>

typedef __attribute__((ext_vector_type(8))) short bf16x8;
typedef __attribute__((ext_vector_type(4))) float f32x4;
typedef __attribute__((ext_vector_type(8))) unsigned short u16x8;

#define BB 32
#define NN 1024
#define MM 256
#define HH 128

__device__ __forceinline__ unsigned short f2bf(float f) {
  union { float f; unsigned int u; } c; c.f = f;
  unsigned int u = c.u + 0x7fffu + ((c.u >> 16) & 1u);  // RNE
  return (unsigned short)(u >> 16);
}
__device__ __forceinline__ unsigned int cvtpk(float lo, float hi) {
  unsigned int r;
  asm("v_cvt_pk_bf16_f32 %0, %1, %2" : "=v"(r) : "v"(lo), "v"(hi));
  return r;
}
__device__ __forceinline__ float4 gload_f4(const float* p) {
  float4 r;
  asm volatile("global_load_dwordx4 %0, %1, off" : "=v"(r) : "v"(p));
  return r;
}
typedef __attribute__((address_space(3))) unsigned int as3_u32;
typedef const __attribute__((address_space(1))) unsigned int as1_u32;
__device__ __forceinline__ void gl_lds16(const void* g, void* l) {
  __builtin_amdgcn_global_load_lds((as1_u32*)g, (as3_u32*)l, 16, 0, 0);
}

// ---------- combined pre-pass: hT (bf16 [B][M][N]) + W1T/W2T ----------
__global__ __launch_bounds__(256)
void k_prep(const float* __restrict__ hg, unsigned short* __restrict__ hTg,
            const float* __restrict__ W1, const float* __restrict__ W2,
            unsigned short* __restrict__ W1T, unsigned short* __restrict__ W2T) {
  int bid = blockIdx.x;
  if (bid < BB * 64) {
    __shared__ unsigned short tile[64][65];
    int b = bid >> 6;
    int t = bid & 63;
    int k0 = (t >> 2) << 6;
    int m0 = (t & 3) << 6;
    int tt = threadIdx.x;
    {
      int r = tt >> 2;
      int cg = (tt & 3) << 4;
      const float* src = hg + (((size_t)b * NN + k0 + r) * MM + m0 + cg);
#pragma unroll
      for (int i = 0; i < 4; ++i) {
        float4 v = reinterpret_cast<const float4*>(src)[i];
        tile[r][cg + i * 4 + 0] = f2bf(v.x);
        tile[r][cg + i * 4 + 1] = f2bf(v.y);
        tile[r][cg + i * 4 + 2] = f2bf(v.z);
        tile[r][cg + i * 4 + 3] = f2bf(v.w);
      }
    }
    __syncthreads();
    {
      int mr = tt >> 2;
      int kc = (tt & 3) << 4;
      alignas(16) unsigned short tmp[16];
#pragma unroll
      for (int i = 0; i < 16; ++i) tmp[i] = tile[kc + i][mr];
      unsigned short* dst = hTg + (((size_t)b * MM + m0 + mr) * NN + k0 + kc);
      *reinterpret_cast<u16x8*>(dst)     = *reinterpret_cast<u16x8*>(tmp);
      *reinterpret_cast<u16x8*>(dst + 8) = *reinterpret_cast<u16x8*>(tmp + 8);
    }
  } else {
    int idx = (bid - BB * 64) * 256 + threadIdx.x;
    if (idx < MM * HH) {
      int hc = idx >> 8;
      int m  = idx & 255;
      W1T[idx] = f2bf(W1[m * HH + hc]);
    } else {
      int j = idx - MM * HH;
      int m  = j >> 7;
      int hd = j & 127;
      W2T[j] = f2bf(W2[hd * MM + m]);
    }
  }
}

// ---------------- fused main ----------------
// 512 blocks x 512 threads (8 waves = 2 row-halves x 4 col-quarters).
// Block tile 64 rows x 256 cols; per-wave 32x64; BK=64, 16 K-steps.
// r17 + A prefetch deepened to 2 steps (X/Y pinned reg sets, 16 VGPR):
// step t: STAGE_H(t+1) -> ISSUE_A(t+2) -> CONSUME(t) -> vmcnt(6) [A(t+1)
// landed, issued 1.5 steps ago] -> CVTWR A(t+1) -> vmcnt(2) [H(t+1) in
// LDS] -> lgkm-barrier.  No wait targets a load younger than ~1 step.
// LDS map (81920 B = 80 KiB exactly -> 2 blocks/CU):
//   H0 @0 (32K), H1 @32K (32K), A0 @64K (8K), A1 @72K (8K)
//   phase2 alias: Kld @0, Cld @32K, smax @64K (A0 dead after phase 1).
#define HB0 0
#define HB1 32768
#define AB0 65536
#define AB1 73728
#define KLD 0
#define CLD 32768
#define SMAXOFF 65536

#define PIPE_BARRIER() do { \
  asm volatile("s_waitcnt lgkmcnt(0)" ::: "memory"); \
  __builtin_amdgcn_s_barrier(); \
  asm volatile("" ::: "memory"); } while (0)

#define VMW(N) do { asm volatile("s_waitcnt vmcnt(" #N ")" ::: "memory"); \
  __builtin_amdgcn_sched_barrier(0); } while (0)

__global__ __launch_bounds__(512)
void k_fused(const float* __restrict__ Ag, const float* __restrict__ hg,
             const unsigned short* __restrict__ hTg,
             const unsigned short* __restrict__ W1Tg,
             const unsigned short* __restrict__ W2Tg,
             const float* __restrict__ b1g, const float* __restrict__ b2g,
             float* __restrict__ outg) {
  __shared__ __align__(16) char smem[81920];
  float* smax = reinterpret_cast<float*>(smem + SMAXOFF);

  const int tid  = threadIdx.x;
  const int lane = tid & 63;
  const int wid  = tid >> 6;       // 0..7
  const int wr   = wid >> 2;       // 0..1 (row half, 32 rows)
  const int wc   = wid & 3;        // 0..3 (col quarter, 64 cols)
  const int l15  = lane & 15;
  const int lg   = lane >> 4;      // 0..3

  const int bid = blockIdx.x;
  const int b   = bid & 31;        // same-batch blocks share bid%8 -> same XCD
  const int r0  = (bid >> 5) << 6; // 16 row-blocks of 64

  const float* Ab = Ag + ((size_t)b * NN + r0) * NN;
  const unsigned short* hTb = hTg + (size_t)b * MM * NN;

  // ---- A staging (verified contiguous map): row = i*32+(tid>>4), 16B
  // chunk tid&15; wave-instr = 4 rows x 256B contiguous runs ----
  const int arow0 = tid >> 4;
  const int akc   = tid & 15;
  const float* apA0 = Ab + (size_t)arow0        * NN + (akc << 2);
  const float* apA1 = Ab + (size_t)(32 + arow0) * NN + (akc << 2);

  // ---- H staging (verified): [256 cols][128B], pre-swizzled source ----
  const unsigned short* baseH[4];
#pragma unroll
  for (int i = 0; i < 4; ++i) {
    int c = i * 512 + tid;
    int col = c >> 3, cic = c & 7;
    baseH[i] = hTb + (size_t)col * NN + ((cic ^ (col & 7)) << 3);
  }
  const int ldsW = wid << 10;

#define STAGE_H(K0, HB)                                                     \
  do {                                                                      \
    _Pragma("unroll")                                                       \
    for (int i = 0; i < 4; ++i)                                             \
      gl_lds16(baseH[i] + (K0), smem + (HB) + ldsW + i * 8192);             \
  } while (0)

  // two pinned A register sets (X/Y), 8 VGPR each
  float4 rAX0, rAX1, rAY0, rAY1;
#define ISSUE_AX(K0) do { rAX0 = gload_f4(apA0 + (K0));                     \
                          rAX1 = gload_f4(apA1 + (K0)); } while (0)
#define ISSUE_AY(K0) do { rAY0 = gload_f4(apA0 + (K0));                     \
                          rAY1 = gload_f4(apA1 + (K0)); } while (0)

  float pm0 = -1e30f, pm1 = -1e30f;
#define CVTWR(AB, R0, R1)                                                   \
  do {                                                                      \
    pm0 = fmaxf(pm0, fmaxf(fmaxf((R0).x, (R0).y), fmaxf((R0).z, (R0).w)));  \
    pm1 = fmaxf(pm1, fmaxf(fmaxf((R1).x, (R1).y), fmaxf((R1).z, (R1).w)));  \
    uint2 q0 = make_uint2(cvtpk((R0).x, (R0).y), cvtpk((R0).z, (R0).w));    \
    uint2 q1 = make_uint2(cvtpk((R1).x, (R1).y), cvtpk((R1).z, (R1).w));    \
    *reinterpret_cast<uint2*>(smem + (AB) + (arow0)      * 128 +            \
                              ((akc << 3) ^ ((arow0 & 7) << 4))) = q0;      \
    *reinterpret_cast<uint2*>(smem + (AB) + (32 + arow0) * 128 +            \
                              ((akc << 3) ^ ((arow0 & 7) << 4))) = q1;      \
  } while (0)

  f32x4 acc[2][4];
#pragma unroll
  for (int m = 0; m < 2; ++m)
#pragma unroll
    for (int n = 0; n < 4; ++n) acc[m][n] = f32x4{0.f, 0.f, 0.f, 0.f};

#define CONSUME(AB, HB)                                                     \
  do {                                                                      \
    _Pragma("unroll")                                                       \
    for (int kk = 0; kk < 2; ++kk) {                                        \
      const int kb = (kk * 32 + (lg << 3)) * 2;                             \
      bf16x8 af[2], bh[4];                                                  \
      _Pragma("unroll")                                                     \
      for (int m = 0; m < 2; ++m) {                                         \
        int row = (wr << 5) + (m << 4) + l15;                               \
        af[m] = *reinterpret_cast<const bf16x8*>(                           \
            smem + (AB) + row * 128 + (kb ^ ((row & 7) << 4)));             \
      }                                                                     \
      _Pragma("unroll")                                                     \
      for (int n = 0; n < 4; ++n) {                                         \
        int col = (wc << 6) + (n << 4) + l15;                               \
        bh[n] = *reinterpret_cast<const bf16x8*>(                           \
            smem + (HB) + col * 128 + (kb ^ ((col & 7) << 4)));             \
      }                                                                     \
      _Pragma("unroll")                                                     \
      for (int m = 0; m < 2; ++m)                                           \
        _Pragma("unroll")                                                   \
        for (int n = 0; n < 4; ++n)                                         \
          acc[m][n] = __builtin_amdgcn_mfma_f32_16x16x32_bf16(af[m], bh[n], \
                                                              acc[m][n], 0, 0, 0); \
    }                                                                       \
  } while (0)

  // ---- prologue: H(0)+A(0), cvt A(0)->AB0; issue A(1)->Y ----
  STAGE_H(0, HB0);               // H(0): 4
  ISSUE_AX(0);                   // A(0)->X: 2
  VMW(0);                        // both landed
  CVTWR(AB0, rAX0, rAX1);
  ISSUE_AY(64);                  // A(1)->Y (in flight across barrier)
  PIPE_BARRIER();

  // ---- phase 1: 16 K-steps of 64, one barrier/step, 2-deep A pipeline ----
  // A(t) set: (t&1) ? Y : X.  A(t) buf: AB(t&1).  H(t) buf: HB(t&1).
#pragma unroll
  for (int t = 0; t < 16; ++t) {
    if (t < 15) STAGE_H((t + 1) * 64, (t & 1) ? HB0 : HB1);   // H(t+1): 4
    if (t < 14) {                                             // A(t+2): 2
      if (t & 1) ISSUE_AY((t + 2) * 64);   // t odd: t+2 odd -> Y
      else       ISSUE_AX((t + 2) * 64);   // t even: t+2 even -> X
    }
    CONSUME((t & 1) ? AB1 : AB0, (t & 1) ? HB1 : HB0);
    if (t < 15) {
      // retire A(t+1): newer = H(t+1):4 + (A(t+2):2 if issued)
      if (t < 14) VMW(6); else VMW(4);
      if (t & 1) CVTWR(AB0, rAX0, rAX1);   // t odd: A(t+1) even -> X
      else       CVTWR(AB1, rAY0, rAY1);   // t even: A(t+1) odd -> Y
      // retire H(t+1): newer = (A(t+2):2 if issued)
      if (t < 14) VMW(2); else VMW(0);
      PIPE_BARRIER();
    }
  }

  // ---- rowmax finalize: reduce over lane bits 0-3 (16 staging lanes/row) ----
  {
    float v0 = pm0, v1 = pm1;
#pragma unroll
    for (int s = 1; s < 16; s <<= 1) {
      v0 = fmaxf(v0, __shfl_xor(v0, s));
      v1 = fmaxf(v1, __shfl_xor(v1, s));
    }
    if ((tid & 15) == 0) {
      smax[arow0]      = v0;      // aliases AB0 (dead after phase 1)
      smax[32 + arow0] = v1;
    }
  }
  __syncthreads();   // phase-1 LDS fully retired before aliasing

  // ---- write k tile (/3, bf16) -> Kld [64][512B] XOR @0 (alias H0) ----
  {
    const float inv3 = 1.0f / 3.0f;
#pragma unroll
    for (int m = 0; m < 2; ++m)
#pragma unroll
      for (int n = 0; n < 4; ++n) {
        int col = (wc << 6) + (n << 4) + l15;
#pragma unroll
        for (int j = 0; j < 4; ++j) {
          int row = (wr << 5) + (m << 4) + (lg << 2) + j;
          *reinterpret_cast<unsigned short*>(smem + KLD + row * 512 +
                                             ((col * 2) ^ ((row & 7) << 4))) =
              f2bf(acc[m][n][j] * inv3);
        }
      }
  }
  __syncthreads();

  // ---- GEMM1: y[64][128] = k @ W1 (W1T fragments straight from L2) ----
  f32x4 acc1[2][2];
#pragma unroll
  for (int m = 0; m < 2; ++m)
#pragma unroll
    for (int n = 0; n < 2; ++n) acc1[m][n] = f32x4{0.f, 0.f, 0.f, 0.f};
  const int wcol1 = wc << 5;  // 0,32,64,96
#pragma unroll
  for (int kq = 0; kq < 8; ++kq) {
    bf16x8 af[2], bw[2];
#pragma unroll
    for (int m = 0; m < 2; ++m) {
      int row = (wr << 5) + (m << 4) + l15;
      af[m] = *reinterpret_cast<const bf16x8*>(smem + KLD + row * 512 +
              (((kq * 32 + (lg << 3)) * 2) ^ ((row & 7) << 4)));
    }
#pragma unroll
    for (int n = 0; n < 2; ++n) {
      int col = wcol1 + (n << 4) + l15;
      bw[n] = *reinterpret_cast<const bf16x8*>(W1Tg + (size_t)col * 256 +
                                               kq * 32 + (lg << 3));
    }
#pragma unroll
    for (int m = 0; m < 2; ++m)
#pragma unroll
      for (int n = 0; n < 2; ++n)
        acc1[m][n] = __builtin_amdgcn_mfma_f32_16x16x32_bf16(af[m], bw[n], acc1[m][n], 0, 0, 0);
  }
  __syncthreads();  // Kld fully read

  // ---- c = relu(y+b1) -> Cld [64][256B] XOR @32K (alias H1, disjoint) ----
  {
#pragma unroll
    for (int n = 0; n < 2; ++n) {
      int col = wcol1 + (n << 4) + l15;
      float bias = b1g[col];
#pragma unroll
      for (int m = 0; m < 2; ++m)
#pragma unroll
        for (int j = 0; j < 4; ++j) {
          int row = (wr << 5) + (m << 4) + (lg << 2) + j;
          float v = fmaxf(acc1[m][n][j] + bias, 0.f);
          *reinterpret_cast<unsigned short*>(smem + CLD + row * 256 +
                                             ((col * 2) ^ ((row & 7) << 4))) = f2bf(v);
        }
    }
  }
  __syncthreads();

  // ---- GEMM2: out2[64][256] = c @ W2 (W2T fragments from L2) ----
  f32x4 acc2[2][4];
#pragma unroll
  for (int m = 0; m < 2; ++m)
#pragma unroll
    for (int n = 0; n < 4; ++n) acc2[m][n] = f32x4{0.f, 0.f, 0.f, 0.f};
#pragma unroll
  for (int kq = 0; kq < 4; ++kq) {
    bf16x8 af[2], bw[4];
#pragma unroll
    for (int m = 0; m < 2; ++m) {
      int row = (wr << 5) + (m << 4) + l15;
      af[m] = *reinterpret_cast<const bf16x8*>(smem + CLD + row * 256 +
              (((kq * 32 + (lg << 3)) * 2) ^ ((row & 7) << 4)));
    }
#pragma unroll
    for (int n = 0; n < 4; ++n) {
      int col = (wc << 6) + (n << 4) + l15;
      bw[n] = *reinterpret_cast<const bf16x8*>(W2Tg + (size_t)col * 128 +
                                               kq * 32 + (lg << 3));
    }
#pragma unroll
    for (int m = 0; m < 2; ++m)
#pragma unroll
      for (int n = 0; n < 4; ++n)
        acc2[m][n] = __builtin_amdgcn_mfma_f32_16x16x32_bf16(af[m], bw[n], acc2[m][n], 0, 0, 0);
  }

  // ---- epilogue: out = (out2+b2)*mask + h*(1-mask) ----
  {
#pragma unroll
    for (int n = 0; n < 4; ++n) {
      int col = (wc << 6) + (n << 4) + l15;
      float b2v = b2g[col];
#pragma unroll
      for (int m = 0; m < 2; ++m)
#pragma unroll
        for (int j = 0; j < 4; ++j) {
          int row = (wr << 5) + (m << 4) + (lg << 2) + j;
          float kv = acc2[m][n][j] + b2v;
          float mask = smax[row];
          size_t gidx = ((size_t)b * NN + r0 + row) * MM + col;
          float hv = hg[gidx];
          outg[gidx] = kv * mask + hv * (1.f - mask);
        }
    }
  }
#undef CONSUME
#undef CVTWR
#undef ISSUE_AX
#undef ISSUE_AY
#undef STAGE_H
}

extern "C" void kernel_launch(void* const* d_in, const int* in_sizes, int n_in,
                              void* d_out, int out_size, void* d_ws, size_t ws_size,
                              hipStream_t stream) {
  (void)in_sizes; (void)n_in; (void)out_size; (void)ws_size;
  const float* A  = (const float*)d_in[0];
  const float* h  = (const float*)d_in[1];
  const float* W1 = (const float*)d_in[2];
  const float* b1 = (const float*)d_in[3];
  const float* W2 = (const float*)d_in[4];
  const float* b2 = (const float*)d_in[5];
  float* out = (float*)d_out;

  unsigned short* hT  = (unsigned short*)d_ws;
  unsigned short* W1T = (unsigned short*)((char*)d_ws + (size_t)BB * MM * NN * 2);
  unsigned short* W2T = W1T + MM * HH;

  k_prep<<<BB * 64 + 256, 256, 0, stream>>>(h, hT, W1, W2, W1T, W2T);
  k_fused<<<BB * 16, 512, 0, stream>>>(A, h, hT, W1T, W2T, b1, b2, out);
}